// Round 1
// baseline (320.806 us; speedup 1.0000x reference)
//
#include <hip/hip_runtime.h>
#include <hip/hip_bf16.h>

#define BB 4096
#define DD 64
#define HH 512

typedef __hip_bfloat16 bf16;
typedef _Float16 f16;
typedef __attribute__((ext_vector_type(8))) short bf16x8;
typedef __attribute__((ext_vector_type(8))) _Float16 f16x8;
typedef __attribute__((ext_vector_type(4))) float f32x4;

__device__ __forceinline__ float bf2f(bf16 x) { return __bfloat162float(x); }
__device__ __forceinline__ float u16tof(unsigned short u) {
  union { unsigned int i; float f; } v; v.i = ((unsigned int)u) << 16; return v.f;
}
#define BC8(p) __builtin_bit_cast(bf16x8, *(const uint4*)(p))
#define BCH8(p) __builtin_bit_cast(f16x8, *(const uint4*)(p))

// async global->LDS, 16B per lane. LDS dest = wave-uniform base + lane*16.
__device__ __forceinline__ void gl16(const void* g, void* l) {
  __builtin_amdgcn_global_load_lds((__attribute__((address_space(1))) void*)g,
                                   (__attribute__((address_space(3))) void*)l,
                                   16, 0, 0);
}

// ws: Xbf | Ybf (B*H bf16) | W2bf | V2bf (H*H bf16, fwd) | W1bf | V1bf | W3bf |
//     V3bf (fwd) | W1sw (64x512 f16, swizzled, k4) | W2sw (H*H f16, swizzled, k4)
//     | Jpart (2 x B x 64 f32)   ~11.8 MB

// ---------------------------------------------------------------------------
// cvt: [0,256) W2bf; [256,512) V2bf; [512,640) W2sw; [640,656) W1sw;
//      [656,784) natural bf16 W1,V1,W3,V3.
// Swizzled layouts (unit = 8 consecutive f16 = 16B):
//   W2sw[(kc*512 + h)*8 + (u ^ (h&7))] = W2[h][kc*64 + u*8 .. +8]
//   W1sw[(kc*64 + dl)*8 + (u ^ (dl&7))] = W1T[dl][kc*64 + u*8 .. +8]
// so a LINEAR global_load_lds stage of a [rows][64]-f16 K-slice lands the
// XOR-swizzled layout; ds_read applies the same XOR -> bank-conflict-free.
// ---------------------------------------------------------------------------
__global__ __launch_bounds__(256) void cvt_weights(
    const float* __restrict__ W2, const float* __restrict__ V2,
    const float* __restrict__ W1, const float* __restrict__ V1,
    const float* __restrict__ W3, const float* __restrict__ V3,
    bf16* __restrict__ W2bf, bf16* __restrict__ V2bf,
    bf16* __restrict__ W1bf, bf16* __restrict__ V1bf,
    bf16* __restrict__ W3bf, bf16* __restrict__ V3bf,
    f16* __restrict__ W2sw, f16* __restrict__ W1sw) {
  int blk = blockIdx.x, t = threadIdx.x;
  if (blk < 512) {
    const float* src = (blk < 256) ? W2 : V2;
    bf16* dst = (blk < 256) ? W2bf : V2bf;
    int i = ((blk & 255) * 256 + t) * 4;
    float4 v = *(const float4*)(src + i);
    bf16 o[4] = {__float2bfloat16(v.x), __float2bfloat16(v.y),
                 __float2bfloat16(v.z), __float2bfloat16(v.w)};
    *(uint2*)(dst + i) = *(uint2*)o;
  } else if (blk < 640) {
    int uid = (blk - 512) * 256 + t;          // 0..32767
    int kc = uid >> 12, rem = uid & 4095;
    int h = rem >> 3, u = rem & 7;
    const float* src = W2 + (size_t)h * HH + kc * 64 + u * 8;
    float4 a = *(const float4*)src;
    float4 b = *(const float4*)(src + 4);
    f16 o[8] = {(f16)a.x, (f16)a.y, (f16)a.z, (f16)a.w,
                (f16)b.x, (f16)b.y, (f16)b.z, (f16)b.w};
    *(uint4*)(W2sw + (size_t)((kc * 512 + h) * 8 + (u ^ (h & 7))) * 8) = *(uint4*)o;
  } else if (blk < 656) {
    int uid = (blk - 640) * 256 + t;          // 0..4095
    int kc = uid >> 9, rem = uid & 511;
    int dl = rem >> 3, u = rem & 7;
    f16 o[8];
#pragma unroll
    for (int e = 0; e < 8; ++e)
      o[e] = (f16)W1[(size_t)(kc * 64 + u * 8 + e) * DD + dl];
    *(uint4*)(W1sw + (size_t)((kc * 64 + dl) * 8 + (u ^ (dl & 7))) * 8) = *(uint4*)o;
  } else {
    int which = (blk - 656) >> 5;
    int local = (blk - 656) & 31;
    const float* src = (which == 0) ? W1 : (which == 1) ? V1 : (which == 2) ? W3 : V3;
    bf16* dst = (which == 0) ? W1bf : (which == 1) ? V1bf : (which == 2) ? W3bf : V3bf;
    int i = (local * 256 + t) * 4;
    float4 v = *(const float4*)(src + i);
    bf16 o[4] = {__float2bfloat16(v.x), __float2bfloat16(v.y),
                 __float2bfloat16(v.z), __float2bfloat16(v.w)};
    *(uint2*)(dst + i) = *(uint2*)o;
  }
}

// ---------------------------------------------------------------------------
// fwd (unchanged): 16-row stripes, grid (256, 2), LDS 41.7 KB.
// ---------------------------------------------------------------------------
__global__ __launch_bounds__(256) void fwd(
    const float* __restrict__ states,
    const bf16* __restrict__ W1bf, const float* __restrict__ b1,
    const bf16* __restrict__ W2bf, const float* __restrict__ b2,
    const bf16* __restrict__ W3bf, const float* __restrict__ b3,
    const bf16* __restrict__ V1bf, const float* __restrict__ c1,
    const bf16* __restrict__ V2bf, const float* __restrict__ c2,
    const bf16* __restrict__ V3bf, const float* __restrict__ c3,
    bf16* __restrict__ Xbf, bf16* __restrict__ Ybf, float* __restrict__ out) {
  __shared__ __align__(16) bf16 mus[16 * 72];
  __shared__ __align__(16) bf16 Xres[16 * 520];
  __shared__ __align__(16) bf16 Bs[128 * 72];
  __shared__ __align__(16) bf16 Ych[16 * 136];
  const int bt = blockIdx.x * 16;
  const int path = blockIdx.y;
  const bf16* Wa = path ? V1bf : W1bf;
  const float* ba = path ? c1 : b1;
  const bf16* Wb = path ? V2bf : W2bf;
  const float* bbv = path ? c2 : b2;
  const bf16* Wc = path ? V3bf : W3bf;
  const float* bcv = path ? c3 : b3;
  const int t = threadIdx.x;
  const int lane = t & 63;
  const int w = t >> 6;
  const int c = lane & 15, q = lane >> 4;

  if (t < 128) {
    int row = t >> 3, cg = (t & 7) * 8;
    bf16 o[8];
#pragma unroll
    for (int j = 0; j < 8; j += 4) {
      float4 v = *(const float4*)(states + (size_t)(bt + row) * 128 + cg + j);
      o[j] = __float2bfloat16(v.x); o[j + 1] = __float2bfloat16(v.y);
      o[j + 2] = __float2bfloat16(v.z); o[j + 3] = __float2bfloat16(v.w);
    }
    *(uint4*)(mus + row * 72 + cg) = *(const uint4*)o;
  }
  __syncthreads();

  for (int nch = 0; nch < 4; ++nch) {
    if (nch) __syncthreads();
#pragma unroll
    for (int i = 0; i < 4; ++i) {
      int g = t + i * 256;
      int row = g >> 3, kb = (g & 7) * 8;
      *(uint4*)(Bs + row * 72 + kb) =
          *(const uint4*)(Wa + (size_t)(nch * 128 + row) * 64 + kb);
    }
    __syncthreads();
    f32x4 acc1[2] = {};
#pragma unroll
    for (int s = 0; s < 2; ++s) {
      bf16x8 af = BC8(mus + c * 72 + s * 32 + q * 8);
#pragma unroll
      for (int nt = 0; nt < 2; ++nt) {
        bf16x8 bfr = BC8(Bs + (w * 32 + nt * 16 + c) * 72 + s * 32 + q * 8);
        acc1[nt] = __builtin_amdgcn_mfma_f32_16x16x32_bf16(af, bfr, acc1[nt], 0, 0, 0);
      }
    }
#pragma unroll
    for (int nt = 0; nt < 2; ++nt) {
      int col = nch * 128 + w * 32 + nt * 16 + c;
      float bias = ba[col];
#pragma unroll
      for (int r = 0; r < 4; ++r) {
        int row = q * 4 + r;
        float x = tanhf(acc1[nt][r] + bias);
        Xres[row * 520 + col] = __float2bfloat16(x);
        if (!path) Xbf[(size_t)(bt + row) * HH + col] = __float2bfloat16(x);
      }
    }
  }
  __syncthreads();

  f32x4 acc3 = {};
  for (int hch = 0; hch < 4; ++hch) {
    f32x4 acc2[2] = {};
    for (int kc = 0; kc < 8; ++kc) {
      __syncthreads();
#pragma unroll
      for (int i = 0; i < 4; ++i) {
        int g = t + i * 256;
        int row = g >> 3, kb = (g & 7) * 8;
        *(uint4*)(Bs + row * 72 + kb) =
            *(const uint4*)(Wb + (size_t)(hch * 128 + row) * HH + kc * 64 + kb);
      }
      __syncthreads();
#pragma unroll
      for (int s = 0; s < 2; ++s) {
        bf16x8 af = BC8(Xres + c * 520 + kc * 64 + s * 32 + q * 8);
#pragma unroll
        for (int nt = 0; nt < 2; ++nt) {
          bf16x8 bfr = BC8(Bs + (w * 32 + nt * 16 + c) * 72 + s * 32 + q * 8);
          acc2[nt] = __builtin_amdgcn_mfma_f32_16x16x32_bf16(af, bfr, acc2[nt], 0, 0, 0);
        }
      }
    }
    __syncthreads();
#pragma unroll
    for (int nt = 0; nt < 2; ++nt) {
      int hl = w * 32 + nt * 16 + c;
      int h = hch * 128 + hl;
      float bias = bbv[h];
#pragma unroll
      for (int r = 0; r < 4; ++r) {
        int row = q * 4 + r;
        float y = tanhf(acc2[nt][r] + bias);
        Ych[row * 136 + hl] = __float2bfloat16(y);
        if (!path) Ybf[(size_t)(bt + row) * HH + h] = __float2bfloat16(y);
      }
    }
    __syncthreads();
#pragma unroll
    for (int s3 = 0; s3 < 4; ++s3) {
      bf16x8 bf3 = BC8(Wc + (size_t)(w * 16 + c) * HH + hch * 128 + s3 * 32 + q * 8);
      bf16x8 af3 = BC8(Ych + c * 136 + s3 * 32 + q * 8);
      acc3 = __builtin_amdgcn_mfma_f32_16x16x32_bf16(af3, bf3, acc3, 0, 0, 0);
    }
  }
  {
    int o = w * 16 + c;
    float bias = bcv[o];
#pragma unroll
    for (int r = 0; r < 4; ++r) {
      int row = q * 4 + r;
      float v = acc3[r] + bias;
      if (path) {
        v = fmaxf(v, 0.0f) + log1pf(expf(-fabsf(v)));
        out[(size_t)(bt + row) * 128 + 64 + o] = v;
      } else {
        out[(size_t)(bt + row) * 128 + o] = v;
      }
    }
  }
}

// ---------------------------------------------------------------------------
// k4 v14: 256x256x(K=512) tile, 512 threads (8 waves, 2M x 4N, wave=128x64).
// global_load_lds staging from pre-swizzled W2sw/W1sw; 3-buffer distance-2
// prefetch with counted s_waitcnt vmcnt(5) per K-tile (drain only at kc=7).
// A = W1T-slice (LDS, 64 rows shared by both b-halves) * d1 (reg pk_mul).
// LDS exactly 128 KB -> 1 block/CU. Epilogue: W3 staged transposed f32 over
// dead B buffers; J reduced per-wave then cross-wave. grid (1024, 2).
// ---------------------------------------------------------------------------
#define LDSB(buf) ((buf) * 32768)            // 3 x 32 KB B K-tiles
#define LDSA(buf) (98304 + (buf) * 8192)     // 3 x 8 KB W1T K-slices
#define LDSD1 122880                         // f16 [4][512] = 4 KB
#define LDSD2 126976                         // f32 [4][256] = 4 KB
#define LDSRED 98304                         // epilogue overlay on A bufs

#define STAGE(kc_, buf_) do {                                                  \
    const char* gb_ = (const char*)W2sw + ((size_t)(kc_) * 512 + h0) * 128;    \
    char* lb_ = (char*)lds + LDSB(buf_);                                       \
    gl16(gb_ + t * 16, lb_ + t * 16);                                          \
    gl16(gb_ + 8192 + t * 16, lb_ + 8192 + t * 16);                            \
    gl16(gb_ + 16384 + t * 16, lb_ + 16384 + t * 16);                          \
    gl16(gb_ + 24576 + t * 16, lb_ + 24576 + t * 16);                          \
    gl16((const char*)W1sw + (kc_) * 8192 + t * 16,                            \
         (char*)lds + LDSA(buf_) + t * 16);                                    \
  } while (0)

__global__ __launch_bounds__(512, 2) void k4_gemm(
    const bf16* __restrict__ Xbf, const bf16* __restrict__ Ybf,
    const f16* __restrict__ W1sw, const f16* __restrict__ W2sw,
    const float* __restrict__ W3, float* __restrict__ Jpart) {
  __shared__ __align__(16) char lds[131072];
  const int bt = blockIdx.x;                 // 256-row group: rows bt*256+m
  const int h0 = blockIdx.y * 256;
  const int t = threadIdx.x;
  const int lane = t & 63;
  const int w = t >> 6;
  const int c = lane & 15, q = lane >> 4;
  const int wr = w >> 2, wc = w & 3;         // 2M x 4N wave grid
  const int b0 = bt * 4;

  // ---- prologue: d1s = f16(1-h1^2) [4][512]; d2s = f32(1-h2^2) [4][256] ----
  {
    int e = t * 4, j = e >> 9, k = e & 511;
    ushort4 xv = *(const ushort4*)((const unsigned short*)Xbf +
                                   (size_t)(b0 + j) * HH + k);
    f16 o[4];
    float x;
    x = u16tof(xv.x); o[0] = (f16)(1.f - x * x);
    x = u16tof(xv.y); o[1] = (f16)(1.f - x * x);
    x = u16tof(xv.z); o[2] = (f16)(1.f - x * x);
    x = u16tof(xv.w); o[3] = (f16)(1.f - x * x);
    *(uint2*)(lds + LDSD1 + e * 2) = *(uint2*)o;
  }
  {
    int e = t * 2, j = e >> 8, n = e & 255;
    ushort2 yv = *(const ushort2*)((const unsigned short*)Ybf +
                                   (size_t)(b0 + j) * HH + h0 + n);
    float y0 = u16tof(yv.x), y1 = u16tof(yv.y);
    float2 d2v = {1.f - y0 * y0, 1.f - y1 * y1};
    *(float2*)(lds + LDSD2 + e * 4) = d2v;
  }
  __syncthreads();   // full drain: only our async stages outstanding after this

  STAGE(0, 0);
  STAGE(1, 1);

  const int cj = c & 7;
  const int j16_0 = ((0 + q) ^ cj) * 16;     // s=0 swizzled unit offset
  const int j16_1 = ((4 + q) ^ cj) * 16;     // s=1
  const int arow = c * 128;
  const int brow = (wc * 64 + c) * 128;
  const int d1base = LDSD1 + wr * 2048 + q * 16;

  f32x4 acc[8][4] = {};

#pragma unroll
  for (int kc = 0; kc < 8; ++kc) {
    const int buf = kc % 3;
    // counted wait: leave next tile's 5 loads in flight (FIFO retire, m135)
    if (kc < 7) { asm volatile("s_waitcnt vmcnt(5)\n\ts_barrier" ::: "memory"); }
    else        { asm volatile("s_waitcnt vmcnt(0)\n\ts_barrier" ::: "memory"); }
    if (kc < 6) STAGE(kc + 2, (kc + 2) % 3);

    f16x8 bfr[4][2], w1f[4][2], d1v[2][2];
#pragma unroll
    for (int nt = 0; nt < 4; ++nt) {
      bfr[nt][0] = BCH8(lds + LDSB(buf) + brow + nt * 2048 + j16_0);
      bfr[nt][1] = BCH8(lds + LDSB(buf) + brow + nt * 2048 + j16_1);
    }
#pragma unroll
    for (int i = 0; i < 4; ++i) {
      w1f[i][0] = BCH8(lds + LDSA(buf) + arow + i * 2048 + j16_0);
      w1f[i][1] = BCH8(lds + LDSA(buf) + arow + i * 2048 + j16_1);
    }
#pragma unroll
    for (int b = 0; b < 2; ++b) {
      d1v[b][0] = BCH8(lds + d1base + b * 1024 + kc * 128);
      d1v[b][1] = BCH8(lds + d1base + b * 1024 + kc * 128 + 64);
    }
    __builtin_amdgcn_s_setprio(1);
#pragma unroll
    for (int mt = 0; mt < 8; ++mt) {
#pragma unroll
      for (int s = 0; s < 2; ++s) {
        f16x8 av = w1f[mt & 3][s] * d1v[mt >> 2][s];   // 4x v_pk_mul_f16
#pragma unroll
        for (int nt = 0; nt < 4; ++nt)
          acc[mt][nt] = __builtin_amdgcn_mfma_f32_16x16x32_f16(
              av, bfr[nt][s], acc[mt][nt], 0, 0, 0);
      }
    }
    __builtin_amdgcn_s_setprio(0);
  }
  __syncthreads();

  // ---- epilogue: w3sT[n][dl] f32 stride 72 overlaid on dead B buffers ----
#pragma unroll
  for (int i = 0; i < 8; ++i) {
    int e = (t + i * 512) * 4;
    int dl = e >> 8, col = e & 255;
    float4 v = *(const float4*)(W3 + (size_t)dl * HH + h0 + col);
    *(float*)(lds + ((col + 0) * 72 + dl) * 4) = v.x;
    *(float*)(lds + ((col + 1) * 72 + dl) * 4) = v.y;
    *(float*)(lds + ((col + 2) * 72 + dl) * 4) = v.z;
    *(float*)(lds + ((col + 3) * 72 + dl) * 4) = v.w;
  }
  __syncthreads();

  float d2r[2][4];
#pragma unroll
  for (int bh = 0; bh < 2; ++bh)
#pragma unroll
    for (int nt = 0; nt < 4; ++nt)
      d2r[bh][nt] = *(const float*)(
          lds + LDSD2 + ((wr * 2 + bh) * 256 + wc * 64 + nt * 16 + c) * 4);

  float vsum[8][4] = {};
#pragma unroll
  for (int mt4 = 0; mt4 < 4; ++mt4)
#pragma unroll
    for (int nt = 0; nt < 4; ++nt) {
      f32x4 w3v = *(const f32x4*)(
          lds + ((wc * 64 + nt * 16 + c) * 72 + mt4 * 16 + q * 4) * 4);
#pragma unroll
      for (int bh = 0; bh < 2; ++bh) {
        const int mt = bh * 4 + mt4;
        float sc = d2r[bh][nt];
#pragma unroll
        for (int r = 0; r < 4; ++r)
          vsum[mt][r] += acc[mt][nt][r] * w3v[r] * sc;
      }
    }

#pragma unroll
  for (int mt = 0; mt < 8; ++mt)
#pragma unroll
    for (int r = 0; r < 4; ++r) {
      float v = vsum[mt][r];
      v += __shfl_xor(v, 1);
      v += __shfl_xor(v, 2);
      v += __shfl_xor(v, 4);
      v += __shfl_xor(v, 8);
      if (c == 0)
        *(float*)(lds + LDSRED +
                  (wc * 256 + wr * 128 + mt * 16 + q * 4 + r) * 4) = v;
    }
  __syncthreads();
  if (t < 256) {
    float J = *(const float*)(lds + LDSRED + t * 4) +
              *(const float*)(lds + LDSRED + (256 + t) * 4) +
              *(const float*)(lds + LDSRED + (512 + t) * 4) +
              *(const float*)(lds + LDSRED + (768 + t) * 4);
    Jpart[(size_t)blockIdx.y * (BB * 64) + (size_t)bt * 256 + t] = J;
  }
}

// ---------------------------------------------------------------------------
// combine: out[b,64+d] = 2*(sum of 2 Jpart planes)*sigma + out (Qd stash)
// ---------------------------------------------------------------------------
__global__ __launch_bounds__(256) void combine(
    const float* __restrict__ Jpart, const float* __restrict__ states,
    float* __restrict__ out) {
  int idx = blockIdx.x * 256 + threadIdx.x;
  int b = idx >> 6, d = idx & 63;
  const int plane = BB * 64;
  float J = Jpart[idx] + Jpart[plane + idx];
  float sig = states[(size_t)b * 128 + 64 + d];
  float qd = out[(size_t)b * 128 + 64 + d];
  out[(size_t)b * 128 + 64 + d] = 2.0f * J * sig + qd;
}

extern "C" void kernel_launch(void* const* d_in, const int* in_sizes, int n_in,
                              void* d_out, int out_size, void* d_ws, size_t ws_size,
                              hipStream_t stream) {
  // inputs: 0:t 1:states 2:W1 3:b1 4:W2 5:b2 6:W3 7:b3 8:V1 9:c1 10:V2 11:c2 12:V3 13:c3
  const float* states = (const float*)d_in[1];
  const float* W1 = (const float*)d_in[2];
  const float* b1 = (const float*)d_in[3];
  const float* W2 = (const float*)d_in[4];
  const float* b2 = (const float*)d_in[5];
  const float* W3 = (const float*)d_in[6];
  const float* b3 = (const float*)d_in[7];
  const float* V1 = (const float*)d_in[8];
  const float* c1 = (const float*)d_in[9];
  const float* V2 = (const float*)d_in[10];
  const float* c2 = (const float*)d_in[11];
  const float* V3 = (const float*)d_in[12];
  const float* c3 = (const float*)d_in[13];
  float* out = (float*)d_out;

  bf16* Xbf = (bf16*)d_ws;                         // B*H  (4 MB)
  bf16* Ybf = Xbf + (size_t)BB * HH;               // B*H  (4 MB)
  bf16* W2bf = Ybf + (size_t)BB * HH;              // H*H  (0.5 MB)
  bf16* V2bf = W2bf + (size_t)HH * HH;             // H*H  (0.5 MB)
  bf16* W1bf = V2bf + (size_t)HH * HH;             // 512x64
  bf16* V1bf = W1bf + (size_t)HH * DD;             // 512x64
  bf16* W3bf = V1bf + (size_t)HH * DD;             // 64x512
  bf16* V3bf = W3bf + (size_t)DD * HH;             // 64x512
  f16* W1sw = (f16*)(V3bf + (size_t)DD * HH);      // 64x512 f16 swizzled
  f16* W2sw = W1sw + (size_t)DD * HH;              // H*H f16 swizzled (0.5 MB)
  float* Jpart = (float*)(W2sw + (size_t)HH * HH); // 2*B*64 f32 (2 MB)

  cvt_weights<<<dim3(784), 256, 0, stream>>>(W2, V2, W1, V1, W3, V3,
                                             W2bf, V2bf, W1bf, V1bf,
                                             W3bf, V3bf, W2sw, W1sw);
  fwd<<<dim3(256, 2), 256, 0, stream>>>(states, W1bf, b1, W2bf, b2, W3bf, b3,
                                        V1bf, c1, V2bf, c2, V3bf, c3,
                                        Xbf, Ybf, out);
  k4_gemm<<<dim3(1024, 2), 512, 0, stream>>>(Xbf, Ybf, W1sw, W2sw, W3, Jpart);
  combine<<<dim3(1024), 256, 0, stream>>>(Jpart, states, out);
}

// Round 2
// 281.659 us; speedup vs baseline: 1.1390x; 1.1390x over previous
//
#include <hip/hip_runtime.h>
#include <hip/hip_bf16.h>

#define BB 4096
#define DD 64
#define HH 512

typedef __hip_bfloat16 bf16;
typedef _Float16 f16;
typedef __attribute__((ext_vector_type(8))) short bf16x8;
typedef __attribute__((ext_vector_type(8))) _Float16 f16x8;
typedef __attribute__((ext_vector_type(4))) float f32x4;

__device__ __forceinline__ float bf2f(bf16 x) { return __bfloat162float(x); }
__device__ __forceinline__ float u16tof(unsigned short u) {
  union { unsigned int i; float f; } v; v.i = ((unsigned int)u) << 16; return v.f;
}
#define BC8(p) __builtin_bit_cast(bf16x8, *(const uint4*)(p))
#define BCH8(p) __builtin_bit_cast(f16x8, *(const uint4*)(p))

// async global->LDS, 16B per lane. LDS dest = wave-uniform base + lane*16.
__device__ __forceinline__ void gl16(const void* g, void* l) {
  __builtin_amdgcn_global_load_lds((__attribute__((address_space(1))) void*)g,
                                   (__attribute__((address_space(3))) void*)l,
                                   16, 0, 0);
}

#define BARRIER() __builtin_amdgcn_s_barrier()
#define LGKM0() do { asm volatile("s_waitcnt lgkmcnt(0)" ::: "memory"); \
                     __builtin_amdgcn_sched_barrier(0); } while (0)

// ws: Xbf | Ybf (B*H bf16) | W2bf | V2bf (H*H bf16, fwd) | W1bf | V1bf | W3bf |
//     V3bf (fwd) | W1sw (64x512 f16, swizzled) | W2sw (H*H f16, swizzled) |
//     W3T (512x64 f32, transposed) | Jpart (2 x B x 64 f32)   ~12 MB

// ---------------------------------------------------------------------------
// cvt: [0,256) W2bf; [256,512) V2bf; [512,640) W2sw; [640,656) W1sw;
//      [656,784) natural bf16 W1,V1,W3,V3; [784,816) W3T[h][o] = W3[o][h].
// Swizzled layouts (unit = 8 consecutive f16 = 16B):
//   W2sw[(kc*512 + h)*8 + (u ^ (h&7))] = W2[h][kc*64 + u*8 .. +8]
//   W1sw[(kc*64 + dl)*8 + (u ^ (dl&7))] = W1T[dl][kc*64 + u*8 .. +8]
// so a LINEAR global_load_lds stage lands the XOR-swizzled layout; ds_read
// applies the same XOR -> conflict-free fragment reads.
// ---------------------------------------------------------------------------
__global__ __launch_bounds__(256) void cvt_weights(
    const float* __restrict__ W2, const float* __restrict__ V2,
    const float* __restrict__ W1, const float* __restrict__ V1,
    const float* __restrict__ W3, const float* __restrict__ V3,
    bf16* __restrict__ W2bf, bf16* __restrict__ V2bf,
    bf16* __restrict__ W1bf, bf16* __restrict__ V1bf,
    bf16* __restrict__ W3bf, bf16* __restrict__ V3bf,
    f16* __restrict__ W2sw, f16* __restrict__ W1sw, float* __restrict__ W3T) {
  int blk = blockIdx.x, t = threadIdx.x;
  if (blk < 512) {
    const float* src = (blk < 256) ? W2 : V2;
    bf16* dst = (blk < 256) ? W2bf : V2bf;
    int i = ((blk & 255) * 256 + t) * 4;
    float4 v = *(const float4*)(src + i);
    bf16 o[4] = {__float2bfloat16(v.x), __float2bfloat16(v.y),
                 __float2bfloat16(v.z), __float2bfloat16(v.w)};
    *(uint2*)(dst + i) = *(uint2*)o;
  } else if (blk < 640) {
    int uid = (blk - 512) * 256 + t;          // 0..32767
    int kc = uid >> 12, rem = uid & 4095;
    int h = rem >> 3, u = rem & 7;
    const float* src = W2 + (size_t)h * HH + kc * 64 + u * 8;
    float4 a = *(const float4*)src;
    float4 b = *(const float4*)(src + 4);
    f16 o[8] = {(f16)a.x, (f16)a.y, (f16)a.z, (f16)a.w,
                (f16)b.x, (f16)b.y, (f16)b.z, (f16)b.w};
    *(uint4*)(W2sw + (size_t)((kc * 512 + h) * 8 + (u ^ (h & 7))) * 8) = *(uint4*)o;
  } else if (blk < 656) {
    int uid = (blk - 640) * 256 + t;          // 0..4095
    int kc = uid >> 9, rem = uid & 511;
    int dl = rem >> 3, u = rem & 7;
    f16 o[8];
#pragma unroll
    for (int e = 0; e < 8; ++e)
      o[e] = (f16)W1[(size_t)(kc * 64 + u * 8 + e) * DD + dl];
    *(uint4*)(W1sw + (size_t)((kc * 64 + dl) * 8 + (u ^ (dl & 7))) * 8) = *(uint4*)o;
  } else if (blk < 784) {
    int which = (blk - 656) >> 5;
    int local = (blk - 656) & 31;
    const float* src = (which == 0) ? W1 : (which == 1) ? V1 : (which == 2) ? W3 : V3;
    bf16* dst = (which == 0) ? W1bf : (which == 1) ? V1bf : (which == 2) ? W3bf : V3bf;
    int i = (local * 256 + t) * 4;
    float4 v = *(const float4*)(src + i);
    bf16 o[4] = {__float2bfloat16(v.x), __float2bfloat16(v.y),
                 __float2bfloat16(v.z), __float2bfloat16(v.w)};
    *(uint2*)(dst + i) = *(uint2*)o;
  } else {
    int e = ((blk - 784) * 256 + t) * 4;      // 0..32767
    int h = e >> 6, o0 = e & 63;
    float o[4];
#pragma unroll
    for (int j = 0; j < 4; ++j) o[j] = W3[(size_t)(o0 + j) * HH + h];
    *(float4*)(W3T + (size_t)h * 64 + o0) = *(float4*)o;
  }
}

// ---------------------------------------------------------------------------
// fwd (unchanged): 16-row stripes, grid (256, 2), LDS 41.7 KB.
// ---------------------------------------------------------------------------
__global__ __launch_bounds__(256) void fwd(
    const float* __restrict__ states,
    const bf16* __restrict__ W1bf, const float* __restrict__ b1,
    const bf16* __restrict__ W2bf, const float* __restrict__ b2,
    const bf16* __restrict__ W3bf, const float* __restrict__ b3,
    const bf16* __restrict__ V1bf, const float* __restrict__ c1,
    const bf16* __restrict__ V2bf, const float* __restrict__ c2,
    const bf16* __restrict__ V3bf, const float* __restrict__ c3,
    bf16* __restrict__ Xbf, bf16* __restrict__ Ybf, float* __restrict__ out) {
  __shared__ __align__(16) bf16 mus[16 * 72];
  __shared__ __align__(16) bf16 Xres[16 * 520];
  __shared__ __align__(16) bf16 Bs[128 * 72];
  __shared__ __align__(16) bf16 Ych[16 * 136];
  const int bt = blockIdx.x * 16;
  const int path = blockIdx.y;
  const bf16* Wa = path ? V1bf : W1bf;
  const float* ba = path ? c1 : b1;
  const bf16* Wb = path ? V2bf : W2bf;
  const float* bbv = path ? c2 : b2;
  const bf16* Wc = path ? V3bf : W3bf;
  const float* bcv = path ? c3 : b3;
  const int t = threadIdx.x;
  const int lane = t & 63;
  const int w = t >> 6;
  const int c = lane & 15, q = lane >> 4;

  if (t < 128) {
    int row = t >> 3, cg = (t & 7) * 8;
    bf16 o[8];
#pragma unroll
    for (int j = 0; j < 8; j += 4) {
      float4 v = *(const float4*)(states + (size_t)(bt + row) * 128 + cg + j);
      o[j] = __float2bfloat16(v.x); o[j + 1] = __float2bfloat16(v.y);
      o[j + 2] = __float2bfloat16(v.z); o[j + 3] = __float2bfloat16(v.w);
    }
    *(uint4*)(mus + row * 72 + cg) = *(const uint4*)o;
  }
  __syncthreads();

  for (int nch = 0; nch < 4; ++nch) {
    if (nch) __syncthreads();
#pragma unroll
    for (int i = 0; i < 4; ++i) {
      int g = t + i * 256;
      int row = g >> 3, kb = (g & 7) * 8;
      *(uint4*)(Bs + row * 72 + kb) =
          *(const uint4*)(Wa + (size_t)(nch * 128 + row) * 64 + kb);
    }
    __syncthreads();
    f32x4 acc1[2] = {};
#pragma unroll
    for (int s = 0; s < 2; ++s) {
      bf16x8 af = BC8(mus + c * 72 + s * 32 + q * 8);
#pragma unroll
      for (int nt = 0; nt < 2; ++nt) {
        bf16x8 bfr = BC8(Bs + (w * 32 + nt * 16 + c) * 72 + s * 32 + q * 8);
        acc1[nt] = __builtin_amdgcn_mfma_f32_16x16x32_bf16(af, bfr, acc1[nt], 0, 0, 0);
      }
    }
#pragma unroll
    for (int nt = 0; nt < 2; ++nt) {
      int col = nch * 128 + w * 32 + nt * 16 + c;
      float bias = ba[col];
#pragma unroll
      for (int r = 0; r < 4; ++r) {
        int row = q * 4 + r;
        float x = tanhf(acc1[nt][r] + bias);
        Xres[row * 520 + col] = __float2bfloat16(x);
        if (!path) Xbf[(size_t)(bt + row) * HH + col] = __float2bfloat16(x);
      }
    }
  }
  __syncthreads();

  f32x4 acc3 = {};
  for (int hch = 0; hch < 4; ++hch) {
    f32x4 acc2[2] = {};
    for (int kc = 0; kc < 8; ++kc) {
      __syncthreads();
#pragma unroll
      for (int i = 0; i < 4; ++i) {
        int g = t + i * 256;
        int row = g >> 3, kb = (g & 7) * 8;
        *(uint4*)(Bs + row * 72 + kb) =
            *(const uint4*)(Wb + (size_t)(hch * 128 + row) * HH + kc * 64 + kb);
      }
      __syncthreads();
#pragma unroll
      for (int s = 0; s < 2; ++s) {
        bf16x8 af = BC8(Xres + c * 520 + kc * 64 + s * 32 + q * 8);
#pragma unroll
        for (int nt = 0; nt < 2; ++nt) {
          bf16x8 bfr = BC8(Bs + (w * 32 + nt * 16 + c) * 72 + s * 32 + q * 8);
          acc2[nt] = __builtin_amdgcn_mfma_f32_16x16x32_bf16(af, bfr, acc2[nt], 0, 0, 0);
        }
      }
    }
    __syncthreads();
#pragma unroll
    for (int nt = 0; nt < 2; ++nt) {
      int hl = w * 32 + nt * 16 + c;
      int h = hch * 128 + hl;
      float bias = bbv[h];
#pragma unroll
      for (int r = 0; r < 4; ++r) {
        int row = q * 4 + r;
        float y = tanhf(acc2[nt][r] + bias);
        Ych[row * 136 + hl] = __float2bfloat16(y);
        if (!path) Ybf[(size_t)(bt + row) * HH + h] = __float2bfloat16(y);
      }
    }
    __syncthreads();
#pragma unroll
    for (int s3 = 0; s3 < 4; ++s3) {
      bf16x8 bf3 = BC8(Wc + (size_t)(w * 16 + c) * HH + hch * 128 + s3 * 32 + q * 8);
      bf16x8 af3 = BC8(Ych + c * 136 + s3 * 32 + q * 8);
      acc3 = __builtin_amdgcn_mfma_f32_16x16x32_bf16(af3, bf3, acc3, 0, 0, 0);
    }
  }
  {
    int o = w * 16 + c;
    float bias = bcv[o];
#pragma unroll
    for (int r = 0; r < 4; ++r) {
      int row = q * 4 + r;
      float v = acc3[r] + bias;
      if (path) {
        v = fmaxf(v, 0.0f) + log1pf(expf(-fabsf(v)));
        out[(size_t)(bt + row) * 128 + 64 + o] = v;
      } else {
        out[(size_t)(bt + row) * 128 + o] = v;
      }
    }
  }
}

// ---------------------------------------------------------------------------
// k4 v15: v14 geometry (256x256xK512 tile, 512 thr, 8 waves 2Mx4N, 3-buffer
// distance-2 gl_lds staging from pre-swizzled W2sw/W1sw) restructured into
// the m201 4-phase-per-K-tile schedule: phase = (s-half x mt-quad), 16 MFMA,
// {ds_reads, spread stage-issue, barrier, lgkmcnt(0), setprio MFMA, barrier}.
// Counted vmcnt(5) ONLY at K-tile boundary (P3 tail); vmcnt(0) at kc=6.
// Epilogue stages W3 from pre-transposed W3T via float4 (fixes the 64-way
// bank conflict of v14's scalar transpose-store). grid (1024, 2).
// ---------------------------------------------------------------------------
#define LDSB(buf) ((buf) * 32768)            // 3 x 32 KB B K-tiles
#define LDSA(buf) (98304 + (buf) * 8192)     // 3 x 8 KB W1T K-slices
#define LDSD1 122880                         // f16 [4][512] = 4 KB
#define LDSD2 126976                         // f32 [4][256] = 4 KB
#define LDSRED 98304                         // epilogue overlay on A bufs

#define STAGE(kc_, buf_) do {                                                  \
    const char* gb_ = (const char*)W2sw + ((size_t)(kc_) * 512 + h0) * 128;    \
    char* lb_ = (char*)lds + LDSB(buf_);                                       \
    gl16(gb_ + t * 16, lb_ + t * 16);                                          \
    gl16(gb_ + 8192 + t * 16, lb_ + 8192 + t * 16);                            \
    gl16(gb_ + 16384 + t * 16, lb_ + 16384 + t * 16);                          \
    gl16(gb_ + 24576 + t * 16, lb_ + 24576 + t * 16);                          \
    gl16((const char*)W1sw + (kc_) * 8192 + t * 16,                            \
         (char*)lds + LDSA(buf_) + t * 16);                                    \
  } while (0)

__global__ __launch_bounds__(512, 2) void k4_gemm(
    const bf16* __restrict__ Xbf, const bf16* __restrict__ Ybf,
    const f16* __restrict__ W1sw, const f16* __restrict__ W2sw,
    const float* __restrict__ W3T, float* __restrict__ Jpart) {
  __shared__ __align__(16) char lds[131072];
  const int bt = blockIdx.x;                 // 256-row group: rows bt*256+m
  const int h0 = blockIdx.y * 256;
  const int t = threadIdx.x;
  const int lane = t & 63;
  const int w = t >> 6;
  const int c = lane & 15, q = lane >> 4;
  const int wr = w >> 2, wc = w & 3;         // 2M x 4N wave grid
  const int b0 = bt * 4;

  // ---- prologue: d1s = f16(1-h1^2) [4][512]; d2s = f32(1-h2^2) [4][256] ----
  {
    int e = t * 4, j = e >> 9, k = e & 511;
    ushort4 xv = *(const ushort4*)((const unsigned short*)Xbf +
                                   (size_t)(b0 + j) * HH + k);
    f16 o[4];
    float x;
    x = u16tof(xv.x); o[0] = (f16)(1.f - x * x);
    x = u16tof(xv.y); o[1] = (f16)(1.f - x * x);
    x = u16tof(xv.z); o[2] = (f16)(1.f - x * x);
    x = u16tof(xv.w); o[3] = (f16)(1.f - x * x);
    *(uint2*)(lds + LDSD1 + e * 2) = *(uint2*)o;
  }
  {
    int e = t * 2, j = e >> 8, n = e & 255;
    ushort2 yv = *(const ushort2*)((const unsigned short*)Ybf +
                                   (size_t)(b0 + j) * HH + h0 + n);
    float y0 = u16tof(yv.x), y1 = u16tof(yv.y);
    float2 d2v = {1.f - y0 * y0, 1.f - y1 * y1};
    *(float2*)(lds + LDSD2 + e * 4) = d2v;
  }
  __syncthreads();   // d1/d2 visible; all prologue vmem retired

  STAGE(0, 0);
  STAGE(1, 1);
  asm volatile("s_waitcnt vmcnt(5)" ::: "memory");   // tile 0 landed
  BARRIER();

  const int cj = c & 7;
  const int j16_0 = ((0 + q) ^ cj) * 16;     // s=0 swizzled unit offset
  const int j16_1 = ((4 + q) ^ cj) * 16;     // s=1
  const int arow = c * 128;
  const int brow = (wc * 64 + c) * 128;
  const char* d1b = (const char*)lds + LDSD1 + wr * 2048 + q * 16;

  f32x4 acc[8][4] = {};

#pragma unroll
  for (int kc = 0; kc < 8; ++kc) {
    const char* Bb = (const char*)lds + LDSB(kc % 3);
    const char* Ab = (const char*)lds + LDSA(kc % 3);
    const char* gB2 = (const char*)W2sw + ((size_t)(kc + 2) * 512 + h0) * 128;
    const char* gA2 = (const char*)W1sw + (size_t)(kc + 2) * 8192;
    char* lB2 = (char*)lds + LDSB((kc + 2) % 3);
    char* lA2 = (char*)lds + LDSA((kc + 2) % 3);
    f16x8 av;

    // ---- P0: s=0, mt 0-3 ----
    f16x8 b0[4], a0[4];
    f16x8 d00 = BCH8(d1b + kc * 128);
#pragma unroll
    for (int nt = 0; nt < 4; ++nt) b0[nt] = BCH8(Bb + brow + nt * 2048 + j16_0);
#pragma unroll
    for (int i = 0; i < 4; ++i) a0[i] = BCH8(Ab + arow + i * 2048 + j16_0);
    if (kc < 6) {
      gl16(gB2 + t * 16, lB2 + t * 16);
      gl16(gB2 + 8192 + t * 16, lB2 + 8192 + t * 16);
    }
    BARRIER(); LGKM0();
    __builtin_amdgcn_s_setprio(1);
#pragma unroll
    for (int mt = 0; mt < 4; ++mt) {
      av = a0[mt] * d00;
#pragma unroll
      for (int nt = 0; nt < 4; ++nt)
        acc[mt][nt] = __builtin_amdgcn_mfma_f32_16x16x32_f16(
            av, b0[nt], acc[mt][nt], 0, 0, 0);
    }
    __builtin_amdgcn_s_setprio(0);
    BARRIER();

    // ---- P1: s=0, mt 4-7 ----
    f16x8 d10 = BCH8(d1b + 1024 + kc * 128);
    if (kc < 6) {
      gl16(gB2 + 16384 + t * 16, lB2 + 16384 + t * 16);
      gl16(gB2 + 24576 + t * 16, lB2 + 24576 + t * 16);
    }
    BARRIER(); LGKM0();
    __builtin_amdgcn_s_setprio(1);
#pragma unroll
    for (int mt = 0; mt < 4; ++mt) {
      av = a0[mt] * d10;
#pragma unroll
      for (int nt = 0; nt < 4; ++nt)
        acc[mt + 4][nt] = __builtin_amdgcn_mfma_f32_16x16x32_f16(
            av, b0[nt], acc[mt + 4][nt], 0, 0, 0);
    }
    __builtin_amdgcn_s_setprio(0);
    BARRIER();

    // ---- P2: s=1, mt 0-3 ----
    f16x8 b1[4], a1[4];
    f16x8 d01 = BCH8(d1b + 64 + kc * 128);
#pragma unroll
    for (int nt = 0; nt < 4; ++nt) b1[nt] = BCH8(Bb + brow + nt * 2048 + j16_1);
#pragma unroll
    for (int i = 0; i < 4; ++i) a1[i] = BCH8(Ab + arow + i * 2048 + j16_1);
    if (kc < 6) gl16(gA2 + t * 16, lA2 + t * 16);
    BARRIER(); LGKM0();
    __builtin_amdgcn_s_setprio(1);
#pragma unroll
    for (int mt = 0; mt < 4; ++mt) {
      av = a1[mt] * d01;
#pragma unroll
      for (int nt = 0; nt < 4; ++nt)
        acc[mt][nt] = __builtin_amdgcn_mfma_f32_16x16x32_f16(
            av, b1[nt], acc[mt][nt], 0, 0, 0);
    }
    __builtin_amdgcn_s_setprio(0);
    BARRIER();

    // ---- P3: s=1, mt 4-7; K-tile boundary sync at tail ----
    f16x8 d11 = BCH8(d1b + 1024 + 64 + kc * 128);
    BARRIER(); LGKM0();
    __builtin_amdgcn_s_setprio(1);
#pragma unroll
    for (int mt = 0; mt < 4; ++mt) {
      av = a1[mt] * d11;
#pragma unroll
      for (int nt = 0; nt < 4; ++nt)
        acc[mt + 4][nt] = __builtin_amdgcn_mfma_f32_16x16x32_f16(
            av, b1[nt], acc[mt + 4][nt], 0, 0, 0);
    }
    __builtin_amdgcn_s_setprio(0);
    if (kc < 6) {
      asm volatile("s_waitcnt vmcnt(5)" ::: "memory");  // tile kc+1 landed
      BARRIER();
    } else if (kc == 6) {
      asm volatile("s_waitcnt vmcnt(0)" ::: "memory");  // tile 7 landed
      BARRIER();
    }
    // kc==7: epilogue __syncthreads handles the final sync
  }
  __syncthreads();

  // ---- epilogue: w3s[col*72+dl] = W3[dl][h0+col], staged from W3T via
  // float4 loads+stores (balanced banks), overlaid on dead B buffers ----
#pragma unroll
  for (int i = 0; i < 8; ++i) {
    int e = (t + i * 512) * 4;
    int col = e >> 6, dl0 = e & 63;
    float4 v = *(const float4*)(W3T + (size_t)(h0 + col) * 64 + dl0);
    *(float4*)(lds + (col * 72 + dl0) * 4) = v;
  }
  __syncthreads();

  float d2r[2][4];
#pragma unroll
  for (int bh = 0; bh < 2; ++bh)
#pragma unroll
    for (int nt = 0; nt < 4; ++nt)
      d2r[bh][nt] = *(const float*)(
          lds + LDSD2 + ((wr * 2 + bh) * 256 + wc * 64 + nt * 16 + c) * 4);

  float vsum[8][4] = {};
#pragma unroll
  for (int mt4 = 0; mt4 < 4; ++mt4)
#pragma unroll
    for (int nt = 0; nt < 4; ++nt) {
      f32x4 w3v = *(const f32x4*)(
          lds + ((wc * 64 + nt * 16 + c) * 72 + mt4 * 16 + q * 4) * 4);
#pragma unroll
      for (int bh = 0; bh < 2; ++bh) {
        const int mt = bh * 4 + mt4;
        float sc = d2r[bh][nt];
#pragma unroll
        for (int r = 0; r < 4; ++r)
          vsum[mt][r] += acc[mt][nt][r] * w3v[r] * sc;
      }
    }

#pragma unroll
  for (int mt = 0; mt < 8; ++mt)
#pragma unroll
    for (int r = 0; r < 4; ++r) {
      float v = vsum[mt][r];
      v += __shfl_xor(v, 1);
      v += __shfl_xor(v, 2);
      v += __shfl_xor(v, 4);
      v += __shfl_xor(v, 8);
      if (c == 0)
        *(float*)(lds + LDSRED +
                  (wc * 256 + wr * 128 + mt * 16 + q * 4 + r) * 4) = v;
    }
  __syncthreads();
  if (t < 256) {
    float J = *(const float*)(lds + LDSRED + t * 4) +
              *(const float*)(lds + LDSRED + (256 + t) * 4) +
              *(const float*)(lds + LDSRED + (512 + t) * 4) +
              *(const float*)(lds + LDSRED + (768 + t) * 4);
    Jpart[(size_t)blockIdx.y * (BB * 64) + (size_t)bt * 256 + t] = J;
  }
}

// ---------------------------------------------------------------------------
// combine: out[b,64+d] = 2*(sum of 2 Jpart planes)*sigma + out (Qd stash)
// ---------------------------------------------------------------------------
__global__ __launch_bounds__(256) void combine(
    const float* __restrict__ Jpart, const float* __restrict__ states,
    float* __restrict__ out) {
  int idx = blockIdx.x * 256 + threadIdx.x;
  int b = idx >> 6, d = idx & 63;
  const int plane = BB * 64;
  float J = Jpart[idx] + Jpart[plane + idx];
  float sig = states[(size_t)b * 128 + 64 + d];
  float qd = out[(size_t)b * 128 + 64 + d];
  out[(size_t)b * 128 + 64 + d] = 2.0f * J * sig + qd;
}

extern "C" void kernel_launch(void* const* d_in, const int* in_sizes, int n_in,
                              void* d_out, int out_size, void* d_ws, size_t ws_size,
                              hipStream_t stream) {
  // inputs: 0:t 1:states 2:W1 3:b1 4:W2 5:b2 6:W3 7:b3 8:V1 9:c1 10:V2 11:c2 12:V3 13:c3
  const float* states = (const float*)d_in[1];
  const float* W1 = (const float*)d_in[2];
  const float* b1 = (const float*)d_in[3];
  const float* W2 = (const float*)d_in[4];
  const float* b2 = (const float*)d_in[5];
  const float* W3 = (const float*)d_in[6];
  const float* b3 = (const float*)d_in[7];
  const float* V1 = (const float*)d_in[8];
  const float* c1 = (const float*)d_in[9];
  const float* V2 = (const float*)d_in[10];
  const float* c2 = (const float*)d_in[11];
  const float* V3 = (const float*)d_in[12];
  const float* c3 = (const float*)d_in[13];
  float* out = (float*)d_out;

  bf16* Xbf = (bf16*)d_ws;                         // B*H  (4 MB)
  bf16* Ybf = Xbf + (size_t)BB * HH;               // B*H  (4 MB)
  bf16* W2bf = Ybf + (size_t)BB * HH;              // H*H  (0.5 MB)
  bf16* V2bf = W2bf + (size_t)HH * HH;             // H*H  (0.5 MB)
  bf16* W1bf = V2bf + (size_t)HH * HH;             // 512x64
  bf16* V1bf = W1bf + (size_t)HH * DD;             // 512x64
  bf16* W3bf = V1bf + (size_t)HH * DD;             // 64x512
  bf16* V3bf = W3bf + (size_t)DD * HH;             // 64x512
  f16* W1sw = (f16*)(V3bf + (size_t)DD * HH);      // 64x512 f16 swizzled
  f16* W2sw = W1sw + (size_t)DD * HH;              // H*H f16 swizzled (0.5 MB)
  float* W3T = (float*)(W2sw + (size_t)HH * HH);   // 512x64 f32 transposed
  float* Jpart = W3T + (size_t)HH * DD;            // 2*B*64 f32 (2 MB)

  cvt_weights<<<dim3(816), 256, 0, stream>>>(W2, V2, W1, V1, W3, V3,
                                             W2bf, V2bf, W1bf, V1bf,
                                             W3bf, V3bf, W2sw, W1sw, W3T);
  fwd<<<dim3(256, 2), 256, 0, stream>>>(states, W1bf, b1, W2bf, b2, W3bf, b3,
                                        V1bf, c1, V2bf, c2, V3bf, c3,
                                        Xbf, Ybf, out);
  k4_gemm<<<dim3(1024, 2), 512, 0, stream>>>(Xbf, Ybf, W1sw, W2sw, W3T, Jpart);
  combine<<<dim3(1024), 256, 0, stream>>>(Jpart, states, out);
}

// Round 3
// 278.004 us; speedup vs baseline: 1.1540x; 1.0131x over previous
//
#include <hip/hip_runtime.h>
#include <hip/hip_bf16.h>

#define BB 4096
#define DD 64
#define HH 512

typedef __hip_bfloat16 bf16;
typedef _Float16 f16;
typedef __attribute__((ext_vector_type(8))) short bf16x8;
typedef __attribute__((ext_vector_type(8))) _Float16 f16x8;
typedef __attribute__((ext_vector_type(4))) float f32x4;

__device__ __forceinline__ float bf2f(bf16 x) { return __bfloat162float(x); }
__device__ __forceinline__ float u16tof(unsigned short u) {
  union { unsigned int i; float f; } v; v.i = ((unsigned int)u) << 16; return v.f;
}
#define BC8(p) __builtin_bit_cast(bf16x8, *(const uint4*)(p))
#define BCH8(p) __builtin_bit_cast(f16x8, *(const uint4*)(p))

// async global->LDS, 16B per lane. LDS dest = wave-uniform base + lane*16.
__device__ __forceinline__ void gl16(const void* g, void* l) {
  __builtin_amdgcn_global_load_lds((__attribute__((address_space(1))) void*)g,
                                   (__attribute__((address_space(3))) void*)l,
                                   16, 0, 0);
}

// hw barrier + compiler memory fence, NO waitcnt pin (compiler keeps its own
// fine-grained lgkmcnt for register-destined ds_reads).
#define BARX() asm volatile("s_barrier" ::: "memory")

// ws: Xbf | Ybf (B*H bf16) | W2bf | V2bf (H*H bf16, fwd) | W1bf | V1bf | W3bf |
//     V3bf (fwd) | W1sw (64x512 f16, swizzled) | W2sw (H*H f16, swizzled) |
//     W3T (512x64 f32, transposed) | Jpart (2 x B x 64 f32)   ~12 MB

// ---------------------------------------------------------------------------
// cvt: [0,256) W2bf; [256,512) V2bf; [512,640) W2sw; [640,656) W1sw;
//      [656,784) natural bf16 W1,V1,W3,V3; [784,816) W3T[h][o] = W3[o][h].
// Swizzled layouts (unit = 8 consecutive f16 = 16B):
//   W2sw[(kc*512 + h)*8 + (u ^ (h&7))] = W2[h][kc*64 + u*8 .. +8]
//   W1sw[(kc*64 + dl)*8 + (u ^ (dl&7))] = W1T[dl][kc*64 + u*8 .. +8]
// so a LINEAR global_load_lds stage lands the XOR-swizzled layout; ds_read
// applies the same XOR -> conflict-free fragment reads.
// ---------------------------------------------------------------------------
__global__ __launch_bounds__(256) void cvt_weights(
    const float* __restrict__ W2, const float* __restrict__ V2,
    const float* __restrict__ W1, const float* __restrict__ V1,
    const float* __restrict__ W3, const float* __restrict__ V3,
    bf16* __restrict__ W2bf, bf16* __restrict__ V2bf,
    bf16* __restrict__ W1bf, bf16* __restrict__ V1bf,
    bf16* __restrict__ W3bf, bf16* __restrict__ V3bf,
    f16* __restrict__ W2sw, f16* __restrict__ W1sw, float* __restrict__ W3T) {
  int blk = blockIdx.x, t = threadIdx.x;
  if (blk < 512) {
    const float* src = (blk < 256) ? W2 : V2;
    bf16* dst = (blk < 256) ? W2bf : V2bf;
    int i = ((blk & 255) * 256 + t) * 4;
    float4 v = *(const float4*)(src + i);
    bf16 o[4] = {__float2bfloat16(v.x), __float2bfloat16(v.y),
                 __float2bfloat16(v.z), __float2bfloat16(v.w)};
    *(uint2*)(dst + i) = *(uint2*)o;
  } else if (blk < 640) {
    int uid = (blk - 512) * 256 + t;          // 0..32767
    int kc = uid >> 12, rem = uid & 4095;
    int h = rem >> 3, u = rem & 7;
    const float* src = W2 + (size_t)h * HH + kc * 64 + u * 8;
    float4 a = *(const float4*)src;
    float4 b = *(const float4*)(src + 4);
    f16 o[8] = {(f16)a.x, (f16)a.y, (f16)a.z, (f16)a.w,
                (f16)b.x, (f16)b.y, (f16)b.z, (f16)b.w};
    *(uint4*)(W2sw + (size_t)((kc * 512 + h) * 8 + (u ^ (h & 7))) * 8) = *(uint4*)o;
  } else if (blk < 656) {
    int uid = (blk - 640) * 256 + t;          // 0..4095
    int kc = uid >> 9, rem = uid & 511;
    int dl = rem >> 3, u = rem & 7;
    f16 o[8];
#pragma unroll
    for (int e = 0; e < 8; ++e)
      o[e] = (f16)W1[(size_t)(kc * 64 + u * 8 + e) * DD + dl];
    *(uint4*)(W1sw + (size_t)((kc * 64 + dl) * 8 + (u ^ (dl & 7))) * 8) = *(uint4*)o;
  } else if (blk < 784) {
    int which = (blk - 656) >> 5;
    int local = (blk - 656) & 31;
    const float* src = (which == 0) ? W1 : (which == 1) ? V1 : (which == 2) ? W3 : V3;
    bf16* dst = (which == 0) ? W1bf : (which == 1) ? V1bf : (which == 2) ? W3bf : V3bf;
    int i = (local * 256 + t) * 4;
    float4 v = *(const float4*)(src + i);
    bf16 o[4] = {__float2bfloat16(v.x), __float2bfloat16(v.y),
                 __float2bfloat16(v.z), __float2bfloat16(v.w)};
    *(uint2*)(dst + i) = *(uint2*)o;
  } else {
    int e = ((blk - 784) * 256 + t) * 4;      // 0..32767
    int h = e >> 6, o0 = e & 63;
    float o[4];
#pragma unroll
    for (int j = 0; j < 4; ++j) o[j] = W3[(size_t)(o0 + j) * HH + h];
    *(float4*)(W3T + (size_t)h * 64 + o0) = *(float4*)o;
  }
}

// ---------------------------------------------------------------------------
// fwd (unchanged): 16-row stripes, grid (256, 2), LDS 41.7 KB.
// ---------------------------------------------------------------------------
__global__ __launch_bounds__(256) void fwd(
    const float* __restrict__ states,
    const bf16* __restrict__ W1bf, const float* __restrict__ b1,
    const bf16* __restrict__ W2bf, const float* __restrict__ b2,
    const bf16* __restrict__ W3bf, const float* __restrict__ b3,
    const bf16* __restrict__ V1bf, const float* __restrict__ c1,
    const bf16* __restrict__ V2bf, const float* __restrict__ c2,
    const bf16* __restrict__ V3bf, const float* __restrict__ c3,
    bf16* __restrict__ Xbf, bf16* __restrict__ Ybf, float* __restrict__ out) {
  __shared__ __align__(16) bf16 mus[16 * 72];
  __shared__ __align__(16) bf16 Xres[16 * 520];
  __shared__ __align__(16) bf16 Bs[128 * 72];
  __shared__ __align__(16) bf16 Ych[16 * 136];
  const int bt = blockIdx.x * 16;
  const int path = blockIdx.y;
  const bf16* Wa = path ? V1bf : W1bf;
  const float* ba = path ? c1 : b1;
  const bf16* Wb = path ? V2bf : W2bf;
  const float* bbv = path ? c2 : b2;
  const bf16* Wc = path ? V3bf : W3bf;
  const float* bcv = path ? c3 : b3;
  const int t = threadIdx.x;
  const int lane = t & 63;
  const int w = t >> 6;
  const int c = lane & 15, q = lane >> 4;

  if (t < 128) {
    int row = t >> 3, cg = (t & 7) * 8;
    bf16 o[8];
#pragma unroll
    for (int j = 0; j < 8; j += 4) {
      float4 v = *(const float4*)(states + (size_t)(bt + row) * 128 + cg + j);
      o[j] = __float2bfloat16(v.x); o[j + 1] = __float2bfloat16(v.y);
      o[j + 2] = __float2bfloat16(v.z); o[j + 3] = __float2bfloat16(v.w);
    }
    *(uint4*)(mus + row * 72 + cg) = *(const uint4*)o;
  }
  __syncthreads();

  for (int nch = 0; nch < 4; ++nch) {
    if (nch) __syncthreads();
#pragma unroll
    for (int i = 0; i < 4; ++i) {
      int g = t + i * 256;
      int row = g >> 3, kb = (g & 7) * 8;
      *(uint4*)(Bs + row * 72 + kb) =
          *(const uint4*)(Wa + (size_t)(nch * 128 + row) * 64 + kb);
    }
    __syncthreads();
    f32x4 acc1[2] = {};
#pragma unroll
    for (int s = 0; s < 2; ++s) {
      bf16x8 af = BC8(mus + c * 72 + s * 32 + q * 8);
#pragma unroll
      for (int nt = 0; nt < 2; ++nt) {
        bf16x8 bfr = BC8(Bs + (w * 32 + nt * 16 + c) * 72 + s * 32 + q * 8);
        acc1[nt] = __builtin_amdgcn_mfma_f32_16x16x32_bf16(af, bfr, acc1[nt], 0, 0, 0);
      }
    }
#pragma unroll
    for (int nt = 0; nt < 2; ++nt) {
      int col = nch * 128 + w * 32 + nt * 16 + c;
      float bias = ba[col];
#pragma unroll
      for (int r = 0; r < 4; ++r) {
        int row = q * 4 + r;
        float x = tanhf(acc1[nt][r] + bias);
        Xres[row * 520 + col] = __float2bfloat16(x);
        if (!path) Xbf[(size_t)(bt + row) * HH + col] = __float2bfloat16(x);
      }
    }
  }
  __syncthreads();

  f32x4 acc3 = {};
  for (int hch = 0; hch < 4; ++hch) {
    f32x4 acc2[2] = {};
    for (int kc = 0; kc < 8; ++kc) {
      __syncthreads();
#pragma unroll
      for (int i = 0; i < 4; ++i) {
        int g = t + i * 256;
        int row = g >> 3, kb = (g & 7) * 8;
        *(uint4*)(Bs + row * 72 + kb) =
            *(const uint4*)(Wb + (size_t)(hch * 128 + row) * HH + kc * 64 + kb);
      }
      __syncthreads();
#pragma unroll
      for (int s = 0; s < 2; ++s) {
        bf16x8 af = BC8(Xres + c * 520 + kc * 64 + s * 32 + q * 8);
#pragma unroll
        for (int nt = 0; nt < 2; ++nt) {
          bf16x8 bfr = BC8(Bs + (w * 32 + nt * 16 + c) * 72 + s * 32 + q * 8);
          acc2[nt] = __builtin_amdgcn_mfma_f32_16x16x32_bf16(af, bfr, acc2[nt], 0, 0, 0);
        }
      }
    }
    __syncthreads();
#pragma unroll
    for (int nt = 0; nt < 2; ++nt) {
      int hl = w * 32 + nt * 16 + c;
      int h = hch * 128 + hl;
      float bias = bbv[h];
#pragma unroll
      for (int r = 0; r < 4; ++r) {
        int row = q * 4 + r;
        float y = tanhf(acc2[nt][r] + bias);
        Ych[row * 136 + hl] = __float2bfloat16(y);
        if (!path) Ybf[(size_t)(bt + row) * HH + h] = __float2bfloat16(y);
      }
    }
    __syncthreads();
#pragma unroll
    for (int s3 = 0; s3 < 4; ++s3) {
      bf16x8 bf3 = BC8(Wc + (size_t)(w * 16 + c) * HH + hch * 128 + s3 * 32 + q * 8);
      bf16x8 af3 = BC8(Ych + c * 136 + s3 * 32 + q * 8);
      acc3 = __builtin_amdgcn_mfma_f32_16x16x32_bf16(af3, bf3, acc3, 0, 0, 0);
    }
  }
  {
    int o = w * 16 + c;
    float bias = bcv[o];
#pragma unroll
    for (int r = 0; r < 4; ++r) {
      int row = q * 4 + r;
      float v = acc3[r] + bias;
      if (path) {
        v = fmaxf(v, 0.0f) + log1pf(expf(-fabsf(v)));
        out[(size_t)(bt + row) * 128 + 64 + o] = v;
      } else {
        out[(size_t)(bt + row) * 128 + o] = v;
      }
    }
  }
}

// ---------------------------------------------------------------------------
// k4 v16: 256x256xK512 tile, 512 thr, 8 waves 2Mx4N, 3-buffer distance-2
// gl_lds staging from pre-swizzled W2sw/W1sw. K-loop = 4 balanced phases
// per K-tile with ONE-PHASE-AHEAD register prefetch (5 ds_reads/phase feed
// the NEXT phase's 16 MFMA; in-flight reads ride under the current MFMA
// cluster -- no lgkmcnt(0) pins, compiler emits counted waits). Counted
// vmcnt(4) at P1 tail (tile kc+1 landed, kc+2's 4 issues in flight). One
// "memory" s_barrier per phase; read->overwrite distance = 3 barriers.
// grid (1024, 2).
// ---------------------------------------------------------------------------
#define LDSB(buf) ((buf) * 32768)            // 3 x 32 KB B K-tiles
#define LDSA(buf) (98304 + (buf) * 8192)     // 3 x 8 KB W1T K-slices
#define LDSD1 122880                         // f16 [4][512] = 4 KB
#define LDSD2 126976                         // f32 [4][256] = 4 KB
#define LDSRED 98304                         // epilogue overlay on A bufs

#define STAGE(kc_, buf_) do {                                                  \
    const char* gb_ = (const char*)W2sw + ((size_t)(kc_) * 512 + h0) * 128;    \
    char* lb_ = (char*)lds + LDSB(buf_);                                       \
    gl16(gb_ + t * 16, lb_ + t * 16);                                          \
    gl16(gb_ + 8192 + t * 16, lb_ + 8192 + t * 16);                            \
    gl16(gb_ + 16384 + t * 16, lb_ + 16384 + t * 16);                          \
    gl16(gb_ + 24576 + t * 16, lb_ + 24576 + t * 16);                          \
    gl16((const char*)W1sw + (kc_) * 8192 + t * 16,                            \
         (char*)lds + LDSA(buf_) + t * 16);                                    \
  } while (0)

__global__ __launch_bounds__(512, 2) void k4_gemm(
    const bf16* __restrict__ Xbf, const bf16* __restrict__ Ybf,
    const f16* __restrict__ W1sw, const f16* __restrict__ W2sw,
    const float* __restrict__ W3T, float* __restrict__ Jpart) {
  __shared__ __align__(16) char lds[131072];
  const int bt = blockIdx.x;                 // 256-row group: rows bt*256+m
  const int h0 = blockIdx.y * 256;
  const int t = threadIdx.x;
  const int lane = t & 63;
  const int w = t >> 6;
  const int c = lane & 15, q = lane >> 4;
  const int wr = w >> 2, wc = w & 3;         // 2M x 4N wave grid
  const int b0 = bt * 4;

  // ---- prologue: d1s = f16(1-h1^2) [4][512]; d2s = f32(1-h2^2) [4][256] ----
  {
    int e = t * 4, j = e >> 9, k = e & 511;
    ushort4 xv = *(const ushort4*)((const unsigned short*)Xbf +
                                   (size_t)(b0 + j) * HH + k);
    f16 o[4];
    float x;
    x = u16tof(xv.x); o[0] = (f16)(1.f - x * x);
    x = u16tof(xv.y); o[1] = (f16)(1.f - x * x);
    x = u16tof(xv.z); o[2] = (f16)(1.f - x * x);
    x = u16tof(xv.w); o[3] = (f16)(1.f - x * x);
    *(uint2*)(lds + LDSD1 + e * 2) = *(uint2*)o;
  }
  {
    int e = t * 2, j = e >> 8, n = e & 255;
    ushort2 yv = *(const ushort2*)((const unsigned short*)Ybf +
                                   (size_t)(b0 + j) * HH + h0 + n);
    float y0 = u16tof(yv.x), y1 = u16tof(yv.y);
    float2 d2v = {1.f - y0 * y0, 1.f - y1 * y1};
    *(float2*)(lds + LDSD2 + e * 4) = d2v;
  }
  __syncthreads();   // d1/d2 visible; all prologue vmem retired

  STAGE(0, 0);
  STAGE(1, 1);
  asm volatile("s_waitcnt vmcnt(5)" ::: "memory");   // tile 0 landed
  BARX();

  const int cj = c & 7;
  const int j16_0 = ((0 + q) ^ cj) * 16;     // s=0 swizzled unit offset
  const int j16_1 = ((4 + q) ^ cj) * 16;     // s=1
  const int arow = c * 128;
  const int brow = (wc * 64 + c) * 128;
  const char* d1b = (const char*)lds + LDSD1 + wr * 2048 + q * 16;

  // ---- pre-loop prefetch: kc=0 s0 fragments + d00/d10 (from buf 0) ----
  f16x8 aS0[4], bS0[4], aS1[4], bS1[4], d00, d10, d01, d11, av;
#pragma unroll
  for (int i = 0; i < 4; ++i) aS0[i] = BCH8(lds + LDSA(0) + arow + i * 2048 + j16_0);
#pragma unroll
  for (int nt = 0; nt < 4; ++nt) bS0[nt] = BCH8(lds + LDSB(0) + brow + nt * 2048 + j16_0);
  d00 = BCH8(d1b + 0 * 128);
  d10 = BCH8(d1b + 1024 + 0 * 128);

  f32x4 acc[8][4] = {};

#pragma unroll
  for (int kc = 0; kc < 8; ++kc) {
    const char* Bb = (const char*)lds + LDSB(kc % 3);
    const char* Ab = (const char*)lds + LDSA(kc % 3);
    const char* Bn = (const char*)lds + LDSB((kc + 1) % 3);
    const char* An = (const char*)lds + LDSA((kc + 1) % 3);
    const char* gB2 = (const char*)W2sw + ((size_t)(kc + 2) * 512 + h0) * 128;
    const char* gA2 = (const char*)W1sw + (size_t)(kc + 2) * 8192;
    char* lB2 = (char*)lds + LDSB((kc + 2) % 3);
    char* lA2 = (char*)lds + LDSA((kc + 2) % 3);

    // ---- P0: prefetch aS1+d01 (for P2); stage B0,B1(kc+2); MFMA s0 mt0-3 ----
#pragma unroll
    for (int i = 0; i < 4; ++i) aS1[i] = BCH8(Ab + arow + i * 2048 + j16_1);
    d01 = BCH8(d1b + 64 + kc * 128);
    if (kc < 6) {
      gl16(gB2 + t * 16, lB2 + t * 16);
      gl16(gB2 + 8192 + t * 16, lB2 + 8192 + t * 16);
    }
    __builtin_amdgcn_s_setprio(1);
#pragma unroll
    for (int mt = 0; mt < 4; ++mt) {
      av = aS0[mt] * d00;
#pragma unroll
      for (int nt = 0; nt < 4; ++nt)
        acc[mt][nt] = __builtin_amdgcn_mfma_f32_16x16x32_f16(
            av, bS0[nt], acc[mt][nt], 0, 0, 0);
    }
    __builtin_amdgcn_s_setprio(0);
    BARX();

    // ---- P1: prefetch bS1+d11 (for P3); stage B2,B3; MFMA s0 mt4-7;
    //      counted vmcnt: tile kc+1 landed (kc+2's 4 issues in flight) ----
#pragma unroll
    for (int nt = 0; nt < 4; ++nt) bS1[nt] = BCH8(Bb + brow + nt * 2048 + j16_1);
    d11 = BCH8(d1b + 1024 + 64 + kc * 128);
    if (kc < 6) {
      gl16(gB2 + 16384 + t * 16, lB2 + 16384 + t * 16);
      gl16(gB2 + 24576 + t * 16, lB2 + 24576 + t * 16);
    }
    __builtin_amdgcn_s_setprio(1);
#pragma unroll
    for (int mt = 0; mt < 4; ++mt) {
      av = aS0[mt] * d10;
#pragma unroll
      for (int nt = 0; nt < 4; ++nt)
        acc[mt + 4][nt] = __builtin_amdgcn_mfma_f32_16x16x32_f16(
            av, bS0[nt], acc[mt + 4][nt], 0, 0, 0);
    }
    __builtin_amdgcn_s_setprio(0);
    if (kc < 6)      asm volatile("s_waitcnt vmcnt(4)" ::: "memory");
    else if (kc == 6) asm volatile("s_waitcnt vmcnt(0)" ::: "memory");
    BARX();

    // ---- P2: prefetch next-kc aS0+d00 (buf kc+1, now landed); stage A;
    //      MFMA s1 mt0-3 ----
    if (kc < 7) {
#pragma unroll
      for (int i = 0; i < 4; ++i) aS0[i] = BCH8(An + arow + i * 2048 + j16_0);
      d00 = BCH8(d1b + (kc + 1) * 128);
    }
    if (kc < 6) gl16(gA2 + t * 16, lA2 + t * 16);
    __builtin_amdgcn_s_setprio(1);
#pragma unroll
    for (int mt = 0; mt < 4; ++mt) {
      av = aS1[mt] * d01;
#pragma unroll
      for (int nt = 0; nt < 4; ++nt)
        acc[mt][nt] = __builtin_amdgcn_mfma_f32_16x16x32_f16(
            av, bS1[nt], acc[mt][nt], 0, 0, 0);
    }
    __builtin_amdgcn_s_setprio(0);
    BARX();

    // ---- P3: prefetch next-kc bS0+d10; MFMA s1 mt4-7 ----
    if (kc < 7) {
#pragma unroll
      for (int nt = 0; nt < 4; ++nt) bS0[nt] = BCH8(Bn + brow + nt * 2048 + j16_0);
      d10 = BCH8(d1b + 1024 + (kc + 1) * 128);
    }
    __builtin_amdgcn_s_setprio(1);
#pragma unroll
    for (int mt = 0; mt < 4; ++mt) {
      av = aS1[mt] * d11;
#pragma unroll
      for (int nt = 0; nt < 4; ++nt)
        acc[mt + 4][nt] = __builtin_amdgcn_mfma_f32_16x16x32_f16(
            av, bS1[nt], acc[mt + 4][nt], 0, 0, 0);
    }
    __builtin_amdgcn_s_setprio(0);
    BARX();
  }
  __syncthreads();

  // ---- epilogue: w3s[col*72+dl] = W3[dl][h0+col], staged from W3T via
  // float4 loads+stores (balanced banks), overlaid on dead B buffers ----
#pragma unroll
  for (int i = 0; i < 8; ++i) {
    int e = (t + i * 512) * 4;
    int col = e >> 6, dl0 = e & 63;
    float4 v = *(const float4*)(W3T + (size_t)(h0 + col) * 64 + dl0);
    *(float4*)(lds + (col * 72 + dl0) * 4) = v;
  }
  __syncthreads();

  float d2r[2][4];
#pragma unroll
  for (int bh = 0; bh < 2; ++bh)
#pragma unroll
    for (int nt = 0; nt < 4; ++nt)
      d2r[bh][nt] = *(const float*)(
          lds + LDSD2 + ((wr * 2 + bh) * 256 + wc * 64 + nt * 16 + c) * 4);

  float vsum[8][4] = {};
#pragma unroll
  for (int mt4 = 0; mt4 < 4; ++mt4)
#pragma unroll
    for (int nt = 0; nt < 4; ++nt) {
      f32x4 w3v = *(const f32x4*)(
          lds + ((wc * 64 + nt * 16 + c) * 72 + mt4 * 16 + q * 4) * 4);
#pragma unroll
      for (int bh = 0; bh < 2; ++bh) {
        const int mt = bh * 4 + mt4;
        float sc = d2r[bh][nt];
#pragma unroll
        for (int r = 0; r < 4; ++r)
          vsum[mt][r] += acc[mt][nt][r] * w3v[r] * sc;
      }
    }

#pragma unroll
  for (int mt = 0; mt < 8; ++mt)
#pragma unroll
    for (int r = 0; r < 4; ++r) {
      float v = vsum[mt][r];
      v += __shfl_xor(v, 1);
      v += __shfl_xor(v, 2);
      v += __shfl_xor(v, 4);
      v += __shfl_xor(v, 8);
      if (c == 0)
        *(float*)(lds + LDSRED +
                  (wc * 256 + wr * 128 + mt * 16 + q * 4 + r) * 4) = v;
    }
  __syncthreads();
  if (t < 256) {
    float J = *(const float*)(lds + LDSRED + t * 4) +
              *(const float*)(lds + LDSRED + (256 + t) * 4) +
              *(const float*)(lds + LDSRED + (512 + t) * 4) +
              *(const float*)(lds + LDSRED + (768 + t) * 4);
    Jpart[(size_t)blockIdx.y * (BB * 64) + (size_t)bt * 256 + t] = J;
  }
}

// ---------------------------------------------------------------------------
// combine: out[b,64+d] = 2*(sum of 2 Jpart planes)*sigma + out (Qd stash)
// ---------------------------------------------------------------------------
__global__ __launch_bounds__(256) void combine(
    const float* __restrict__ Jpart, const float* __restrict__ states,
    float* __restrict__ out) {
  int idx = blockIdx.x * 256 + threadIdx.x;
  int b = idx >> 6, d = idx & 63;
  const int plane = BB * 64;
  float J = Jpart[idx] + Jpart[plane + idx];
  float sig = states[(size_t)b * 128 + 64 + d];
  float qd = out[(size_t)b * 128 + 64 + d];
  out[(size_t)b * 128 + 64 + d] = 2.0f * J * sig + qd;
}

extern "C" void kernel_launch(void* const* d_in, const int* in_sizes, int n_in,
                              void* d_out, int out_size, void* d_ws, size_t ws_size,
                              hipStream_t stream) {
  // inputs: 0:t 1:states 2:W1 3:b1 4:W2 5:b2 6:W3 7:b3 8:V1 9:c1 10:V2 11:c2 12:V3 13:c3
  const float* states = (const float*)d_in[1];
  const float* W1 = (const float*)d_in[2];
  const float* b1 = (const float*)d_in[3];
  const float* W2 = (const float*)d_in[4];
  const float* b2 = (const float*)d_in[5];
  const float* W3 = (const float*)d_in[6];
  const float* b3 = (const float*)d_in[7];
  const float* V1 = (const float*)d_in[8];
  const float* c1 = (const float*)d_in[9];
  const float* V2 = (const float*)d_in[10];
  const float* c2 = (const float*)d_in[11];
  const float* V3 = (const float*)d_in[12];
  const float* c3 = (const float*)d_in[13];
  float* out = (float*)d_out;

  bf16* Xbf = (bf16*)d_ws;                         // B*H  (4 MB)
  bf16* Ybf = Xbf + (size_t)BB * HH;               // B*H  (4 MB)
  bf16* W2bf = Ybf + (size_t)BB * HH;              // H*H  (0.5 MB)
  bf16* V2bf = W2bf + (size_t)HH * HH;             // H*H  (0.5 MB)
  bf16* W1bf = V2bf + (size_t)HH * HH;             // 512x64
  bf16* V1bf = W1bf + (size_t)HH * DD;             // 512x64
  bf16* W3bf = V1bf + (size_t)HH * DD;             // 64x512
  bf16* V3bf = W3bf + (size_t)DD * HH;             // 64x512
  f16* W1sw = (f16*)(V3bf + (size_t)DD * HH);      // 64x512 f16 swizzled
  f16* W2sw = W1sw + (size_t)DD * HH;              // H*H f16 swizzled (0.5 MB)
  float* W3T = (float*)(W2sw + (size_t)HH * HH);   // 512x64 f32 transposed
  float* Jpart = W3T + (size_t)HH * DD;            // 2*B*64 f32 (2 MB)

  cvt_weights<<<dim3(816), 256, 0, stream>>>(W2, V2, W1, V1, W3, V3,
                                             W2bf, V2bf, W1bf, V1bf,
                                             W3bf, V3bf, W2sw, W1sw, W3T);
  fwd<<<dim3(256, 2), 256, 0, stream>>>(states, W1bf, b1, W2bf, b2, W3bf, b3,
                                        V1bf, c1, V2bf, c2, V3bf, c3,
                                        Xbf, Ybf, out);
  k4_gemm<<<dim3(1024, 2), 512, 0, stream>>>(Xbf, Ybf, W1sw, W2sw, W3T, Jpart);
  combine<<<dim3(1024), 256, 0, stream>>>(Jpart, states, out);
}

// Round 4
// 269.237 us; speedup vs baseline: 1.1915x; 1.0326x over previous
//
#include <hip/hip_runtime.h>
#include <hip/hip_bf16.h>

#define BB 4096
#define DD 64
#define HH 512

typedef __hip_bfloat16 bf16;
typedef _Float16 f16;
typedef __attribute__((ext_vector_type(8))) short bf16x8;
typedef __attribute__((ext_vector_type(8))) _Float16 f16x8;
typedef __attribute__((ext_vector_type(4))) float f32x4;

__device__ __forceinline__ float bf2f(bf16 x) { return __bfloat162float(x); }
__device__ __forceinline__ float u16tof(unsigned short u) {
  union { unsigned int i; float f; } v; v.i = ((unsigned int)u) << 16; return v.f;
}
#define BC8(p) __builtin_bit_cast(bf16x8, *(const uint4*)(p))
#define BCH8(p) __builtin_bit_cast(f16x8, *(const uint4*)(p))

// async global->LDS, 16B per lane. LDS dest = wave-uniform base + lane*16.
__device__ __forceinline__ void gl16(const void* g, void* l) {
  __builtin_amdgcn_global_load_lds((__attribute__((address_space(1))) void*)g,
                                   (__attribute__((address_space(3))) void*)l,
                                   16, 0, 0);
}

// ws: Xbf | Ybf (B*H bf16) | W2bf | V2bf (H*H bf16, fwd) | W1bf | V1bf | W3bf |
//     V3bf (fwd) | W1sw (64x512 f16, swizzled) | W2fr (H*H f16, frag-ordered) |
//     W3T (512x64 f32, transposed) | Jpart (2 x B x 64 f32)   ~12 MB

// ---------------------------------------------------------------------------
// cvt: [0,256) W2bf; [256,512) V2bf; [512,640) W2fr; [640,656) W1sw;
//      [656,784) natural bf16 W1,V1,W3,V3; [784,816) W3T[h][o] = W3[o][h].
// W1sw (LDS-destined, XOR-swizzled, unit = 8 f16 = 16B):
//   W1sw[(kc*64 + dl)*4... ] -- unchanged from v16:
//   W1sw[((kc*64 + dl)*8 + (u ^ (dl&7)))*8] = W1T[dl][kc*64 + u*8 .. +8]
// W2fr (register-destined B fragments, read straight from L2):
//   unit index uid = ((kc*2+s)*512 + col)*4 + q  (16B units)
//   holds W2[col][kc*64 + s*32 + q*8 .. +8]  as f16.
//   A wave's fragment (kc,s,nt) = 1 KB contiguous: lane(c,q) reads
//   byte (kc*2+s)*32768 + (col)*64 + q*16 with col = h0+wc*64+nt*16+c.
// ---------------------------------------------------------------------------
__global__ __launch_bounds__(256) void cvt_weights(
    const float* __restrict__ W2, const float* __restrict__ V2,
    const float* __restrict__ W1, const float* __restrict__ V1,
    const float* __restrict__ W3, const float* __restrict__ V3,
    bf16* __restrict__ W2bf, bf16* __restrict__ V2bf,
    bf16* __restrict__ W1bf, bf16* __restrict__ V1bf,
    bf16* __restrict__ W3bf, bf16* __restrict__ V3bf,
    f16* __restrict__ W2fr, f16* __restrict__ W1sw, float* __restrict__ W3T) {
  int blk = blockIdx.x, t = threadIdx.x;
  if (blk < 512) {
    const float* src = (blk < 256) ? W2 : V2;
    bf16* dst = (blk < 256) ? W2bf : V2bf;
    int i = ((blk & 255) * 256 + t) * 4;
    float4 v = *(const float4*)(src + i);
    bf16 o[4] = {__float2bfloat16(v.x), __float2bfloat16(v.y),
                 __float2bfloat16(v.z), __float2bfloat16(v.w)};
    *(uint2*)(dst + i) = *(uint2*)o;
  } else if (blk < 640) {
    int uid = (blk - 512) * 256 + t;          // 0..32767 16B-units, dst-linear
    int col = (uid >> 2) & 511;
    int kc2s = uid >> 11;                     // kc*2+s
    int kc = kc2s >> 1, s = kc2s & 1, q = uid & 3;
    const float* src = W2 + (size_t)col * HH + kc * 64 + s * 32 + q * 8;
    float4 a = *(const float4*)src;
    float4 b = *(const float4*)(src + 4);
    f16 o[8] = {(f16)a.x, (f16)a.y, (f16)a.z, (f16)a.w,
                (f16)b.x, (f16)b.y, (f16)b.z, (f16)b.w};
    *(uint4*)(W2fr + (size_t)uid * 8) = *(uint4*)o;
  } else if (blk < 656) {
    int uid = (blk - 640) * 256 + t;          // 0..4095
    int kc = uid >> 9, rem = uid & 511;
    int dl = rem >> 3, u = rem & 7;
    f16 o[8];
#pragma unroll
    for (int e = 0; e < 8; ++e)
      o[e] = (f16)W1[(size_t)(kc * 64 + u * 8 + e) * DD + dl];
    *(uint4*)(W1sw + (size_t)((kc * 64 + dl) * 8 + (u ^ (dl & 7))) * 8) = *(uint4*)o;
  } else if (blk < 784) {
    int which = (blk - 656) >> 5;
    int local = (blk - 656) & 31;
    const float* src = (which == 0) ? W1 : (which == 1) ? V1 : (which == 2) ? W3 : V3;
    bf16* dst = (which == 0) ? W1bf : (which == 1) ? V1bf : (which == 2) ? W3bf : V3bf;
    int i = (local * 256 + t) * 4;
    float4 v = *(const float4*)(src + i);
    bf16 o[4] = {__float2bfloat16(v.x), __float2bfloat16(v.y),
                 __float2bfloat16(v.z), __float2bfloat16(v.w)};
    *(uint2*)(dst + i) = *(uint2*)o;
  } else {
    int e = ((blk - 784) * 256 + t) * 4;      // 0..32767
    int h = e >> 6, o0 = e & 63;
    float o[4];
#pragma unroll
    for (int j = 0; j < 4; ++j) o[j] = W3[(size_t)(o0 + j) * HH + h];
    *(float4*)(W3T + (size_t)h * 64 + o0) = *(float4*)o;
  }
}

// ---------------------------------------------------------------------------
// fwd (unchanged): 16-row stripes, grid (256, 2), LDS 41.7 KB.
// ---------------------------------------------------------------------------
__global__ __launch_bounds__(256) void fwd(
    const float* __restrict__ states,
    const bf16* __restrict__ W1bf, const float* __restrict__ b1,
    const bf16* __restrict__ W2bf, const float* __restrict__ b2,
    const bf16* __restrict__ W3bf, const float* __restrict__ b3,
    const bf16* __restrict__ V1bf, const float* __restrict__ c1,
    const bf16* __restrict__ V2bf, const float* __restrict__ c2,
    const bf16* __restrict__ V3bf, const float* __restrict__ c3,
    bf16* __restrict__ Xbf, bf16* __restrict__ Ybf, float* __restrict__ out) {
  __shared__ __align__(16) bf16 mus[16 * 72];
  __shared__ __align__(16) bf16 Xres[16 * 520];
  __shared__ __align__(16) bf16 Bs[128 * 72];
  __shared__ __align__(16) bf16 Ych[16 * 136];
  const int bt = blockIdx.x * 16;
  const int path = blockIdx.y;
  const bf16* Wa = path ? V1bf : W1bf;
  const float* ba = path ? c1 : b1;
  const bf16* Wb = path ? V2bf : W2bf;
  const float* bbv = path ? c2 : b2;
  const bf16* Wc = path ? V3bf : W3bf;
  const float* bcv = path ? c3 : b3;
  const int t = threadIdx.x;
  const int lane = t & 63;
  const int w = t >> 6;
  const int c = lane & 15, q = lane >> 4;

  if (t < 128) {
    int row = t >> 3, cg = (t & 7) * 8;
    bf16 o[8];
#pragma unroll
    for (int j = 0; j < 8; j += 4) {
      float4 v = *(const float4*)(states + (size_t)(bt + row) * 128 + cg + j);
      o[j] = __float2bfloat16(v.x); o[j + 1] = __float2bfloat16(v.y);
      o[j + 2] = __float2bfloat16(v.z); o[j + 3] = __float2bfloat16(v.w);
    }
    *(uint4*)(mus + row * 72 + cg) = *(const uint4*)o;
  }
  __syncthreads();

  for (int nch = 0; nch < 4; ++nch) {
    if (nch) __syncthreads();
#pragma unroll
    for (int i = 0; i < 4; ++i) {
      int g = t + i * 256;
      int row = g >> 3, kb = (g & 7) * 8;
      *(uint4*)(Bs + row * 72 + kb) =
          *(const uint4*)(Wa + (size_t)(nch * 128 + row) * 64 + kb);
    }
    __syncthreads();
    f32x4 acc1[2] = {};
#pragma unroll
    for (int s = 0; s < 2; ++s) {
      bf16x8 af = BC8(mus + c * 72 + s * 32 + q * 8);
#pragma unroll
      for (int nt = 0; nt < 2; ++nt) {
        bf16x8 bfr = BC8(Bs + (w * 32 + nt * 16 + c) * 72 + s * 32 + q * 8);
        acc1[nt] = __builtin_amdgcn_mfma_f32_16x16x32_bf16(af, bfr, acc1[nt], 0, 0, 0);
      }
    }
#pragma unroll
    for (int nt = 0; nt < 2; ++nt) {
      int col = nch * 128 + w * 32 + nt * 16 + c;
      float bias = ba[col];
#pragma unroll
      for (int r = 0; r < 4; ++r) {
        int row = q * 4 + r;
        float x = tanhf(acc1[nt][r] + bias);
        Xres[row * 520 + col] = __float2bfloat16(x);
        if (!path) Xbf[(size_t)(bt + row) * HH + col] = __float2bfloat16(x);
      }
    }
  }
  __syncthreads();

  f32x4 acc3 = {};
  for (int hch = 0; hch < 4; ++hch) {
    f32x4 acc2[2] = {};
    for (int kc = 0; kc < 8; ++kc) {
      __syncthreads();
#pragma unroll
      for (int i = 0; i < 4; ++i) {
        int g = t + i * 256;
        int row = g >> 3, kb = (g & 7) * 8;
        *(uint4*)(Bs + row * 72 + kb) =
            *(const uint4*)(Wb + (size_t)(hch * 128 + row) * HH + kc * 64 + kb);
      }
      __syncthreads();
#pragma unroll
      for (int s = 0; s < 2; ++s) {
        bf16x8 af = BC8(Xres + c * 520 + kc * 64 + s * 32 + q * 8);
#pragma unroll
        for (int nt = 0; nt < 2; ++nt) {
          bf16x8 bfr = BC8(Bs + (w * 32 + nt * 16 + c) * 72 + s * 32 + q * 8);
          acc2[nt] = __builtin_amdgcn_mfma_f32_16x16x32_bf16(af, bfr, acc2[nt], 0, 0, 0);
        }
      }
    }
    __syncthreads();
#pragma unroll
    for (int nt = 0; nt < 2; ++nt) {
      int hl = w * 32 + nt * 16 + c;
      int h = hch * 128 + hl;
      float bias = bbv[h];
#pragma unroll
      for (int r = 0; r < 4; ++r) {
        int row = q * 4 + r;
        float y = tanhf(acc2[nt][r] + bias);
        Ych[row * 136 + hl] = __float2bfloat16(y);
        if (!path) Ybf[(size_t)(bt + row) * HH + h] = __float2bfloat16(y);
      }
    }
    __syncthreads();
#pragma unroll
    for (int s3 = 0; s3 < 4; ++s3) {
      bf16x8 bf3 = BC8(Wc + (size_t)(w * 16 + c) * HH + hch * 128 + s3 * 32 + q * 8);
      bf16x8 af3 = BC8(Ych + c * 136 + s3 * 32 + q * 8);
      acc3 = __builtin_amdgcn_mfma_f32_16x16x32_bf16(af3, bf3, acc3, 0, 0, 0);
    }
  }
  {
    int o = w * 16 + c;
    float bias = bcv[o];
#pragma unroll
    for (int r = 0; r < 4; ++r) {
      int row = q * 4 + r;
      float v = acc3[r] + bias;
      if (path) {
        v = fmaxf(v, 0.0f) + log1pf(expf(-fabsf(v)));
        out[(size_t)(bt + row) * 128 + 64 + o] = v;
      } else {
        out[(size_t)(bt + row) * 128 + o] = v;
      }
    }
  }
}

// ---------------------------------------------------------------------------
// k4 v17: B streamed from L2 into registers (W2fr frag-ordered, 1KB
// contiguous per fragment read, double-buffered one K-step ahead); LDS holds
// only the full W1T (64 KB, staged ONCE via gl_lds at block start) + d1 + d2.
// ZERO barriers / vmcnt in the K-loop -- waves free-run over read-only LDS;
// sched_barrier(0) per kc stops cross-kc DAG collapse. 512 thr, 8 waves
// 2Mx4N, wave tile 128x64, full-unroll kc 0..7. grid (1024, 2).
// LDS 80 KB: W1T[0,64K) | d1[64K,+4K) | d2[72K,+4K) | red[76K,+4K);
// epilogue w3s overlays the dead W1T/d1 region [0,73696).
// ---------------------------------------------------------------------------
#define LDSW1 0
#define LDSD1 65536
#define LDSD2 73728
#define LDSRED 77824

__global__ __launch_bounds__(512, 2) void k4_gemm(
    const bf16* __restrict__ Xbf, const bf16* __restrict__ Ybf,
    const f16* __restrict__ W1sw, const f16* __restrict__ W2fr,
    const float* __restrict__ W3T, float* __restrict__ Jpart) {
  __shared__ __align__(16) char lds[81920];
  const int bt = blockIdx.x;                 // 256-row group: rows bt*256+m
  const int h0 = blockIdx.y * 256;
  const int t = threadIdx.x;
  const int lane = t & 63;
  const int w = t >> 6;
  const int c = lane & 15, q = lane >> 4;
  const int wr = w >> 2, wc = w & 3;         // 2M x 4N wave grid
  const int b0 = bt * 4;

  // ---- prologue: stage full W1T (64 KB) once; d1, d2 ----
#pragma unroll
  for (int i = 0; i < 8; ++i)
    gl16((const char*)W1sw + (t + i * 512) * 16,
         (char*)lds + LDSW1 + (t + i * 512) * 16);
  {
    int e = t * 4, j = e >> 9, k = e & 511;
    ushort4 xv = *(const ushort4*)((const unsigned short*)Xbf +
                                   (size_t)(b0 + j) * HH + k);
    f16 o[4];
    float x;
    x = u16tof(xv.x); o[0] = (f16)(1.f - x * x);
    x = u16tof(xv.y); o[1] = (f16)(1.f - x * x);
    x = u16tof(xv.z); o[2] = (f16)(1.f - x * x);
    x = u16tof(xv.w); o[3] = (f16)(1.f - x * x);
    *(uint2*)(lds + LDSD1 + e * 2) = *(uint2*)o;
  }
  {
    int e = t * 2, j = e >> 8, n = e & 255;
    ushort2 yv = *(const ushort2*)((const unsigned short*)Ybf +
                                   (size_t)(b0 + j) * HH + h0 + n);
    float y0 = u16tof(yv.x), y1 = u16tof(yv.y);
    float2 d2v = {1.f - y0 * y0, 1.f - y1 * y1};
    *(float2*)(lds + LDSD2 + e * 4) = d2v;
  }
  __syncthreads();   // drains gl_lds (vmcnt0) + d1/d2 visible

  const int cj = c & 7;
  const int j16_0 = ((0 + q) ^ cj) * 16;     // s=0 swizzled unit offset
  const int j16_1 = ((4 + q) ^ cj) * 16;     // s=1
  const int arow = c * 128;
  const char* d1b = (const char*)lds + LDSD1 + wr * 2048 + q * 16;

  // B fragment global addressing: frag(kc,s,nt) is 1 KB contiguous.
  // byte = (kc*2+s)*32768 + (h0 + wc*64 + nt*16)*64 + (c*64 + q*16)
  const char* gB = (const char*)W2fr + (size_t)(h0 + wc * 64) * 64 +
                   (c * 64 + q * 16);
#define BLD(kc_, s_, nt_) \
  BCH8(gB + ((kc_) * 2 + (s_)) * 32768 + (nt_) * 1024)

  // double-buffered B fragments: parity = kc&1 (static after full unroll)
  f16x8 bb0[2][4], bb1[2][4];
#pragma unroll
  for (int nt = 0; nt < 4; ++nt) bb0[0][nt] = BLD(0, 0, nt);
#pragma unroll
  for (int nt = 0; nt < 4; ++nt) bb1[0][nt] = BLD(0, 1, nt);

  f32x4 acc[8][4] = {};

#pragma unroll
  for (int kc = 0; kc < 8; ++kc) {
    const int cur = kc & 1, nxt = cur ^ 1;
    // issue next K-step's B loads first (max latency cover, ~600 cyc)
    if (kc < 7) {
#pragma unroll
      for (int nt = 0; nt < 4; ++nt) bb0[nxt][nt] = BLD(kc + 1, 0, nt);
#pragma unroll
      for (int nt = 0; nt < 4; ++nt) bb1[nxt][nt] = BLD(kc + 1, 1, nt);
    }
    // A fragments + d1 for this K-step (read-only LDS, no sync needed)
    const char* Ab = (const char*)lds + LDSW1 + kc * 8192;
    f16x8 a0[4], a1[4];
#pragma unroll
    for (int i = 0; i < 4; ++i) a0[i] = BCH8(Ab + arow + i * 2048 + j16_0);
#pragma unroll
    for (int i = 0; i < 4; ++i) a1[i] = BCH8(Ab + arow + i * 2048 + j16_1);
    f16x8 d00 = BCH8(d1b + kc * 128);
    f16x8 d10 = BCH8(d1b + 1024 + kc * 128);
    f16x8 d01 = BCH8(d1b + 64 + kc * 128);
    f16x8 d11 = BCH8(d1b + 1024 + 64 + kc * 128);

    f16x8 av;
    __builtin_amdgcn_s_setprio(1);
#pragma unroll
    for (int mt = 0; mt < 4; ++mt) {
      av = a0[mt] * d00;
#pragma unroll
      for (int nt = 0; nt < 4; ++nt)
        acc[mt][nt] = __builtin_amdgcn_mfma_f32_16x16x32_f16(
            av, bb0[cur][nt], acc[mt][nt], 0, 0, 0);
    }
#pragma unroll
    for (int mt = 0; mt < 4; ++mt) {
      av = a0[mt] * d10;
#pragma unroll
      for (int nt = 0; nt < 4; ++nt)
        acc[mt + 4][nt] = __builtin_amdgcn_mfma_f32_16x16x32_f16(
            av, bb0[cur][nt], acc[mt + 4][nt], 0, 0, 0);
    }
#pragma unroll
    for (int mt = 0; mt < 4; ++mt) {
      av = a1[mt] * d01;
#pragma unroll
      for (int nt = 0; nt < 4; ++nt)
        acc[mt][nt] = __builtin_amdgcn_mfma_f32_16x16x32_f16(
            av, bb1[cur][nt], acc[mt][nt], 0, 0, 0);
    }
#pragma unroll
    for (int mt = 0; mt < 4; ++mt) {
      av = a1[mt] * d11;
#pragma unroll
      for (int nt = 0; nt < 4; ++nt)
        acc[mt + 4][nt] = __builtin_amdgcn_mfma_f32_16x16x32_f16(
            av, bb1[cur][nt], acc[mt + 4][nt], 0, 0, 0);
    }
    __builtin_amdgcn_s_setprio(0);
    __builtin_amdgcn_sched_barrier(0);   // pin kc-region boundary
  }
  __syncthreads();   // all waves done reading W1T/d1 before overlay

  // ---- epilogue: w3s[col*72+dl] = W3[dl][h0+col], staged from W3T via
  // float4 loads+stores (balanced banks), overlaid on dead W1T region ----
#pragma unroll
  for (int i = 0; i < 8; ++i) {
    int e = (t + i * 512) * 4;
    int col = e >> 6, dl0 = e & 63;
    float4 v = *(const float4*)(W3T + (size_t)(h0 + col) * 64 + dl0);
    *(float4*)(lds + (col * 72 + dl0) * 4) = v;
  }
  __syncthreads();

  float d2r[2][4];
#pragma unroll
  for (int bh = 0; bh < 2; ++bh)
#pragma unroll
    for (int nt = 0; nt < 4; ++nt)
      d2r[bh][nt] = *(const float*)(
          lds + LDSD2 + ((wr * 2 + bh) * 256 + wc * 64 + nt * 16 + c) * 4);

  float vsum[8][4] = {};
#pragma unroll
  for (int mt4 = 0; mt4 < 4; ++mt4)
#pragma unroll
    for (int nt = 0; nt < 4; ++nt) {
      f32x4 w3v = *(const f32x4*)(
          lds + ((wc * 64 + nt * 16 + c) * 72 + mt4 * 16 + q * 4) * 4);
#pragma unroll
      for (int bh = 0; bh < 2; ++bh) {
        const int mt = bh * 4 + mt4;
        float sc = d2r[bh][nt];
#pragma unroll
        for (int r = 0; r < 4; ++r)
          vsum[mt][r] += acc[mt][nt][r] * w3v[r] * sc;
      }
    }

#pragma unroll
  for (int mt = 0; mt < 8; ++mt)
#pragma unroll
    for (int r = 0; r < 4; ++r) {
      float v = vsum[mt][r];
      v += __shfl_xor(v, 1);
      v += __shfl_xor(v, 2);
      v += __shfl_xor(v, 4);
      v += __shfl_xor(v, 8);
      if (c == 0)
        *(float*)(lds + LDSRED +
                  (wc * 256 + wr * 128 + mt * 16 + q * 4 + r) * 4) = v;
    }
  __syncthreads();
  if (t < 256) {
    float J = *(const float*)(lds + LDSRED + t * 4) +
              *(const float*)(lds + LDSRED + (256 + t) * 4) +
              *(const float*)(lds + LDSRED + (512 + t) * 4) +
              *(const float*)(lds + LDSRED + (768 + t) * 4);
    Jpart[(size_t)blockIdx.y * (BB * 64) + (size_t)bt * 256 + t] = J;
  }
}

// ---------------------------------------------------------------------------
// combine: out[b,64+d] = 2*(sum of 2 Jpart planes)*sigma + out (Qd stash)
// ---------------------------------------------------------------------------
__global__ __launch_bounds__(256) void combine(
    const float* __restrict__ Jpart, const float* __restrict__ states,
    float* __restrict__ out) {
  int idx = blockIdx.x * 256 + threadIdx.x;
  int b = idx >> 6, d = idx & 63;
  const int plane = BB * 64;
  float J = Jpart[idx] + Jpart[plane + idx];
  float sig = states[(size_t)b * 128 + 64 + d];
  float qd = out[(size_t)b * 128 + 64 + d];
  out[(size_t)b * 128 + 64 + d] = 2.0f * J * sig + qd;
}

extern "C" void kernel_launch(void* const* d_in, const int* in_sizes, int n_in,
                              void* d_out, int out_size, void* d_ws, size_t ws_size,
                              hipStream_t stream) {
  // inputs: 0:t 1:states 2:W1 3:b1 4:W2 5:b2 6:W3 7:b3 8:V1 9:c1 10:V2 11:c2 12:V3 13:c3
  const float* states = (const float*)d_in[1];
  const float* W1 = (const float*)d_in[2];
  const float* b1 = (const float*)d_in[3];
  const float* W2 = (const float*)d_in[4];
  const float* b2 = (const float*)d_in[5];
  const float* W3 = (const float*)d_in[6];
  const float* b3 = (const float*)d_in[7];
  const float* V1 = (const float*)d_in[8];
  const float* c1 = (const float*)d_in[9];
  const float* V2 = (const float*)d_in[10];
  const float* c2 = (const float*)d_in[11];
  const float* V3 = (const float*)d_in[12];
  const float* c3 = (const float*)d_in[13];
  float* out = (float*)d_out;

  bf16* Xbf = (bf16*)d_ws;                         // B*H  (4 MB)
  bf16* Ybf = Xbf + (size_t)BB * HH;               // B*H  (4 MB)
  bf16* W2bf = Ybf + (size_t)BB * HH;              // H*H  (0.5 MB)
  bf16* V2bf = W2bf + (size_t)HH * HH;             // H*H  (0.5 MB)
  bf16* W1bf = V2bf + (size_t)HH * HH;             // 512x64
  bf16* V1bf = W1bf + (size_t)HH * DD;             // 512x64
  bf16* W3bf = V1bf + (size_t)HH * DD;             // 64x512
  bf16* V3bf = W3bf + (size_t)DD * HH;             // 64x512
  f16* W1sw = (f16*)(V3bf + (size_t)DD * HH);      // 64x512 f16 swizzled
  f16* W2fr = W1sw + (size_t)DD * HH;              // H*H f16 frag-ordered
  float* W3T = (float*)(W2fr + (size_t)HH * HH);   // 512x64 f32 transposed
  float* Jpart = W3T + (size_t)HH * DD;            // 2*B*64 f32 (2 MB)

  cvt_weights<<<dim3(816), 256, 0, stream>>>(W2, V2, W1, V1, W3, V3,
                                             W2bf, V2bf, W1bf, V1bf,
                                             W3bf, V3bf, W2fr, W1sw, W3T);
  fwd<<<dim3(256, 2), 256, 0, stream>>>(states, W1bf, b1, W2bf, b2, W3bf, b3,
                                        V1bf, c1, V2bf, c2, V3bf, c3,
                                        Xbf, Ybf, out);
  k4_gemm<<<dim3(1024, 2), 512, 0, stream>>>(Xbf, Ybf, W1sw, W2fr, W3T, Jpart);
  combine<<<dim3(1024), 256, 0, stream>>>(Jpart, states, out);
}